// Round 1
// baseline (1030.203 us; speedup 1.0000x reference)
//
#include <hip/hip_runtime.h>

#define B_    4
#define S_    4096
#define D_    2048
#define DQ_   512
#define DF_   8192
#define KSEL_ 512

typedef __attribute__((ext_vector_type(8))) short bf16x8;
typedef __attribute__((ext_vector_type(4))) float f32x4;
typedef __attribute__((address_space(3))) void as3_void;
typedef const __attribute__((address_space(1))) void as1_cvoid;

__device__ __forceinline__ unsigned short f2bf(float f) {
    unsigned u = __float_as_uint(f);
    u += 0x7FFFu + ((u >> 16) & 1u);   // RNE
    return (unsigned short)(u >> 16);
}

__device__ __forceinline__ void gload16(const void* g, void* l) {
    __builtin_amdgcn_global_load_lds((as1_cvoid*)g, (as3_void*)l, 16, 0, 0);
}

// ---------------- transpose + fp32->bf16 convert: out[c][r] = bf16(in[r][c]) ----
__global__ void transpose_bf16_kernel(const float* __restrict__ in,
                                      unsigned short* __restrict__ out,
                                      int R, int C) {
    __shared__ float tile[32][33];
    int tx = threadIdx.x, ty = threadIdx.y;       // 32 x 8
    int c0 = blockIdx.x * 32, r0 = blockIdx.y * 32;
#pragma unroll
    for (int j = 0; j < 4; j++)
        tile[ty + j * 8][tx] = in[(size_t)(r0 + ty + j * 8) * C + c0 + tx];
    __syncthreads();
#pragma unroll
    for (int j = 0; j < 4; j++)
        out[(size_t)(c0 + ty + j * 8) * R + r0 + tx] = f2bf(tile[tx][ty + j * 8]);
}

// ---------------- router GEMM (fp32): H = relu(X @ Wr1 + br1) -------------------
// M=16384 K=2048 N=512, BM=128 BN=128 BK=32, 256 thr, 8x8 per thread
__global__ __launch_bounds__(256) void router_gemm(const float* __restrict__ X,
                                                   const float* __restrict__ W,
                                                   const float* __restrict__ bias,
                                                   float* __restrict__ H) {
    __shared__ float As[32][128];        // As[k][m]
    __shared__ float BsF[32 * 144];      // padded: addr = k*144 + n + (n/32)*4
    const int t = threadIdx.x;
    const int m0 = blockIdx.y * 128, n0 = blockIdx.x * 128;
    const int tm = (t >> 4) * 8, tn = (t & 15) * 8;
    float acc[8][8];
#pragma unroll
    for (int i = 0; i < 8; i++)
#pragma unroll
        for (int j = 0; j < 8; j++) acc[i][j] = 0.f;

    for (int k0 = 0; k0 < D_; k0 += 32) {
#pragma unroll
        for (int i = 0; i < 4; i++) {
            int c = t + i * 256;
            int r = c >> 3, kq = (c & 7) << 2;                       // A: 128 rows x 32 k
            float4 av = *(const float4*)(X + (size_t)(m0 + r) * D_ + k0 + kq);
            As[kq + 0][r] = av.x; As[kq + 1][r] = av.y;
            As[kq + 2][r] = av.z; As[kq + 3][r] = av.w;
            int kb = c >> 5, n4 = (c & 31) << 2;                     // B: 32 k x 128 n
            float4 bv = *(const float4*)(W + (size_t)(k0 + kb) * DQ_ + n0 + n4);
            *(float4*)&BsF[kb * 144 + n4 + ((n4 >> 5) << 2)] = bv;
        }
        __syncthreads();
#pragma unroll
        for (int kk = 0; kk < 32; kk++) {
            float ra[8], rb[8];
            *(float4*)&ra[0] = *(const float4*)&As[kk][tm];
            *(float4*)&ra[4] = *(const float4*)&As[kk][tm + 4];
            const float* bp = &BsF[kk * 144 + tn + ((tn >> 5) << 2)];
            *(float4*)&rb[0] = *(const float4*)bp;
            *(float4*)&rb[4] = *(const float4*)(bp + 4);
#pragma unroll
            for (int i = 0; i < 8; i++)
#pragma unroll
                for (int j = 0; j < 8; j++)
                    acc[i][j] = fmaf(ra[i], rb[j], acc[i][j]);
        }
        __syncthreads();
    }
#pragma unroll
    for (int i = 0; i < 8; i++) {
        int m = m0 + tm + i;
#pragma unroll
        for (int j = 0; j < 8; j++) {
            int n = n0 + tn + j;
            H[(size_t)m * DQ_ + n] = fmaxf(acc[i][j] + bias[n], 0.f);
        }
    }
}

// ---------------- scores = H @ Wr2 + br2 (one wave per token) -------------------
__global__ void score_kernel(const float* __restrict__ H, const float* __restrict__ Wr2,
                             const float* __restrict__ br2, float* __restrict__ scores) {
    int wv = threadIdx.x >> 6, l = threadIdx.x & 63;
    int tok = blockIdx.x * 4 + wv;
    const float* hrow = H + (size_t)tok * DQ_;
    float4 a0 = ((const float4*)hrow)[l];
    float4 a1 = ((const float4*)hrow)[64 + l];
    float4 w0 = ((const float4*)Wr2)[l];
    float4 w1 = ((const float4*)Wr2)[64 + l];
    float s = a0.x * w0.x + a0.y * w0.y + a0.z * w0.z + a0.w * w0.w
            + a1.x * w1.x + a1.y * w1.y + a1.z * w1.z + a1.w * w1.w;
#pragma unroll
    for (int off = 32; off >= 1; off >>= 1) s += __shfl_xor(s, off);
    if (l == 0) scores[tok] = s + br2[0];
}

// ---------------- exact top-k per batch row (bitonic sort, 4096 keys) -----------
// key = (orderable(score) << 32) | (4095 - idx): desc score, asc index on ties
__global__ void topk_kernel(const float* __restrict__ scores, int* __restrict__ sel_idx,
                            float* __restrict__ maskF) {
    __shared__ unsigned long long keys[S_];
    __shared__ unsigned char flags[S_];
    int b = blockIdx.x, t = threadIdx.x;                       // 256 threads
    for (int i = t; i < S_; i += 256) {
        float f = scores[b * S_ + i];
        unsigned u = __float_as_uint(f);
        u = (u & 0x80000000u) ? ~u : (u | 0x80000000u);
        keys[i] = ((unsigned long long)u << 32) | (unsigned)(S_ - 1 - i);
        flags[i] = 0;
    }
    __syncthreads();
    for (int k = 2; k <= S_; k <<= 1)
        for (int j = k >> 1; j > 0; j >>= 1) {
            for (int i = t; i < S_; i += 256) {
                int l = i ^ j;
                if (l > i) {
                    unsigned long long a = keys[i], c = keys[l];
                    bool up = ((i & k) == 0);
                    if (up ? (a > c) : (a < c)) { keys[i] = c; keys[l] = a; }
                }
            }
            __syncthreads();
        }
    // ascending sort -> top KSEL_ at the tail
    for (int i = t; i < KSEL_; i += 256) {
        unsigned long long kk = keys[S_ - KSEL_ + i];
        int s = (S_ - 1) - (int)(kk & 0xFFFFFFFFu);
        sel_idx[b * KSEL_ + i] = s;
        flags[s] = 1;
    }
    __syncthreads();
    for (int i = t; i < S_; i += 256)
        maskF[b * S_ + i] = flags[i] ? 1.0f : 0.0f;
}

// ---------------- gather selected rows, convert to bf16 -------------------------
__global__ void gather_kernel(const float* __restrict__ x, const int* __restrict__ sel_idx,
                              unsigned short* __restrict__ sel) {
    int jrow = blockIdx.x;               // 0..2047
    int b = jrow >> 9;
    int tok = sel_idx[jrow];
    const float* src = x + ((size_t)(b * S_ + tok)) * D_;
    int t = threadIdx.x;                 // 256
    float4 v0 = ((const float4*)src)[2 * t];
    float4 v1 = ((const float4*)src)[2 * t + 1];
    unsigned p0 = (unsigned)f2bf(v0.x) | ((unsigned)f2bf(v0.y) << 16);
    unsigned p1 = (unsigned)f2bf(v0.z) | ((unsigned)f2bf(v0.w) << 16);
    unsigned p2 = (unsigned)f2bf(v1.x) | ((unsigned)f2bf(v1.y) << 16);
    unsigned p3 = (unsigned)f2bf(v1.z) | ((unsigned)f2bf(v1.w) << 16);
    *(uint4*)(sel + (size_t)jrow * D_ + t * 8) = make_uint4(p0, p1, p2, p3);
}

// ---------------- plain copy x -> out --------------------------------------------
__global__ void copy_kernel(const float4* __restrict__ src, float4* __restrict__ dst, int n4) {
    int i = blockIdx.x * blockDim.x + threadIdx.x;
    int stride = gridDim.x * blockDim.x;
    for (; i < n4; i += stride) dst[i] = src[i];
}

// ---------------- bf16 MFMA GEMM, m97 structure (128x128 tile, BK=32) -----------
// A [M][K] bf16 row-major, Bt [N][K] bf16 row-major (B transposed).
// epi==0: C = bf16(relu(acc + bias[n])) -> Cbf [M][N]
// epi==1: out[(b*S + sel_idx[m])*D + n] = acc + bias[n]  (fp32 scatter)
__global__ __launch_bounds__(256) void mfma_gemm(const unsigned short* __restrict__ A,
                                                 const unsigned short* __restrict__ Bt,
                                                 int M, int N, int K,
                                                 const float* __restrict__ bias,
                                                 unsigned short* __restrict__ Cbf,
                                                 float* __restrict__ outF,
                                                 const int* __restrict__ sel_idx,
                                                 int epi) {
    __shared__ unsigned short As[128 * 32];
    __shared__ unsigned short Bs[128 * 32];
    const int t = threadIdx.x;
    const int w = t >> 6, l = t & 63;
    const int m0 = blockIdx.y * 128, n0 = blockIdx.x * 128;
    const int wm = (w >> 1) * 64, wn = (w & 1) * 64;

    f32x4 acc[4][4];
    const f32x4 z = {0.f, 0.f, 0.f, 0.f};
#pragma unroll
    for (int i = 0; i < 4; i++)
#pragma unroll
        for (int j = 0; j < 4; j++) acc[i][j] = z;

    const int ra = t >> 2;          // row within 64-row half-tile
    const int ca = (t & 3) * 8;     // k offset (8 bf16 = 16B)
    const unsigned short* gA0 = A + (size_t)(m0 + ra) * K + ca;
    const unsigned short* gA1 = A + (size_t)(m0 + 64 + ra) * K + ca;
    const unsigned short* gB0 = Bt + (size_t)(n0 + ra) * K + ca;
    const unsigned short* gB1 = Bt + (size_t)(n0 + 64 + ra) * K + ca;
    char* lA = (char*)As + w * 1024;   // wave-uniform LDS base (+lane*16 implicit)
    char* lB = (char*)Bs + w * 1024;

    for (int k0 = 0; k0 < K; k0 += 32) {
        gload16(gA0 + k0, lA);
        gload16(gA1 + k0, lA + 4096);
        gload16(gB0 + k0, lB);
        gload16(gB1 + k0, lB + 4096);
        __syncthreads();               // drains vmcnt before LDS reads
        bf16x8 af[4], bb[4];
#pragma unroll
        for (int i = 0; i < 4; i++) {
            af[i] = *(const bf16x8*)(As + (wm + i * 16 + (l & 15)) * 32 + (l >> 4) * 8);
            bb[i] = *(const bf16x8*)(Bs + (wn + i * 16 + (l & 15)) * 32 + (l >> 4) * 8);
        }
#pragma unroll
        for (int i = 0; i < 4; i++)
#pragma unroll
            for (int j = 0; j < 4; j++)
                acc[i][j] = __builtin_amdgcn_mfma_f32_16x16x32_bf16(af[i], bb[j], acc[i][j], 0, 0, 0);
        __syncthreads();
    }

    if (epi == 0) {
#pragma unroll
        for (int i = 0; i < 4; i++) {
            int mbase = m0 + wm + i * 16 + (l >> 4) * 4;
#pragma unroll
            for (int j = 0; j < 4; j++) {
                int n = n0 + wn + j * 16 + (l & 15);
                float bv = bias[n];
#pragma unroll
                for (int q = 0; q < 4; q++) {
                    float v = acc[i][j][q] + bv;
                    v = fmaxf(v, 0.f);
                    Cbf[(size_t)(mbase + q) * N + n] = f2bf(v);
                }
            }
        }
    } else {
#pragma unroll
        for (int i = 0; i < 4; i++) {
            int mbase = m0 + wm + i * 16 + (l >> 4) * 4;
#pragma unroll
            for (int q = 0; q < 4; q++) {
                int m = mbase + q;
                int brow = m >> 9;
                int tok = sel_idx[m];
                float* orow = outF + ((size_t)(brow * S_ + tok)) * D_;
#pragma unroll
                for (int j = 0; j < 4; j++) {
                    int n = n0 + wn + j * 16 + (l & 15);
                    orow[n] = acc[i][j][q] + bias[n];
                }
            }
        }
    }
}

extern "C" void kernel_launch(void* const* d_in, const int* in_sizes, int n_in,
                              void* d_out, int out_size, void* d_ws, size_t ws_size,
                              hipStream_t stream) {
    const float* x   = (const float*)d_in[0];
    const float* Wr1 = (const float*)d_in[1];
    const float* br1 = (const float*)d_in[2];
    const float* Wr2 = (const float*)d_in[3];
    const float* br2 = (const float*)d_in[4];
    const float* Wf1 = (const float*)d_in[5];
    const float* bf1 = (const float*)d_in[6];
    const float* Wf2 = (const float*)d_in[7];
    const float* bf2 = (const float*)d_in[8];
    float* out = (float*)d_out;
    char* ws = (char*)d_ws;

    // workspace layout (h and h1 alias: h dead after score_kernel)
    unsigned short* w1t = (unsigned short*)(ws);                 // [DF][D] bf16, 32MB
    unsigned short* w2t = (unsigned short*)(ws + 33554432);      // [D][DF] bf16, 32MB
    char* hh            = ws + 67108864;                         // 32MB shared
    float* h            = (float*)hh;                            // [B*S][DQ] fp32
    unsigned short* h1  = (unsigned short*)hh;                   // [B*k][DF] bf16
    unsigned short* sel = (unsigned short*)(ws + 100663296);     // [B*k][D] bf16, 8MB
    float* scores       = (float*)(ws + 109051904);              // [B*S]
    int* sel_idx        = (int*)(ws + 109117440);                // [B*k]
    float* maskF        = out + (size_t)B_ * S_ * D_;

    (void)in_sizes; (void)n_in; (void)out_size; (void)ws_size;

    // 1-2. weight transpose + bf16 convert
    transpose_bf16_kernel<<<dim3(DF_ / 32, D_ / 32), dim3(32, 8), 0, stream>>>(Wf1, w1t, D_, DF_);
    transpose_bf16_kernel<<<dim3(D_ / 32, DF_ / 32), dim3(32, 8), 0, stream>>>(Wf2, w2t, DF_, D_);
    // 3. router hidden (fp32, exact enough for selection)
    router_gemm<<<dim3(DQ_ / 128, (B_ * S_) / 128), 256, 0, stream>>>(x, Wr1, br1, h);
    // 4. scores
    score_kernel<<<(B_ * S_) / 4, 256, 0, stream>>>(h, Wr2, br2, scores);
    // 5. exact top-k + mask
    topk_kernel<<<B_, 256, 0, stream>>>(scores, sel_idx, maskF);
    // 6. gather selected tokens -> bf16
    gather_kernel<<<B_ * KSEL_, 256, 0, stream>>>(x, sel_idx, sel);
    // 7. copy x -> out (selected rows overwritten by gemm2 scatter)
    copy_kernel<<<2048, 256, 0, stream>>>((const float4*)x, (float4*)out,
                                          (B_ * S_ * D_) / 4);
    // 8. FFN gemm1: h1 = bf16(relu(sel @ Wf1 + bf1))   M=2048 N=8192 K=2048
    mfma_gemm<<<dim3(DF_ / 128, (B_ * KSEL_) / 128), 256, 0, stream>>>(
        sel, w1t, B_ * KSEL_, DF_, D_, bf1, h1, nullptr, nullptr, 0);
    // 9. FFN gemm2 + scatter: out[b, idx, :] = h1 @ Wf2 + bf2   M=2048 N=2048 K=8192
    mfma_gemm<<<dim3(D_ / 128, (B_ * KSEL_) / 128), 256, 0, stream>>>(
        h1, w2t, B_ * KSEL_, D_, DF_, bf2, nullptr, out, sel_idx, 1);
}

// Round 2
// 696.310 us; speedup vs baseline: 1.4795x; 1.4795x over previous
//
#include <hip/hip_runtime.h>

#define B_    4
#define S_    4096
#define D_    2048
#define DQ_   512
#define DF_   8192
#define KSEL_ 512
#define M_    (B_ * S_)     // 16384

typedef __attribute__((ext_vector_type(8))) short bf16x8;
typedef __attribute__((ext_vector_type(4))) float f32x4;
typedef __attribute__((address_space(3))) void as3_void;
typedef const __attribute__((address_space(1))) void as1_cvoid;

__device__ __forceinline__ unsigned short f2bf(float f) {
    unsigned u = __float_as_uint(f);
    u += 0x7FFFu + ((u >> 16) & 1u);   // RNE
    return (unsigned short)(u >> 16);
}
__device__ __forceinline__ float bf2f(unsigned short h) {
    return __uint_as_float(((unsigned)h) << 16);
}

__device__ __forceinline__ void gload16(const void* g, void* l) {
    __builtin_amdgcn_global_load_lds((as1_cvoid*)g, (as3_void*)l, 16, 0, 0);
}

// ---------------- split x into bf16 hi + bf16 residual --------------------------
__global__ void split_x_kernel(const float* __restrict__ x,
                               unsigned short* __restrict__ xh,
                               unsigned short* __restrict__ xl, int n8) {
    int i = blockIdx.x * blockDim.x + threadIdx.x;
    int stride = gridDim.x * blockDim.x;
    for (; i < n8; i += stride) {
        float4 a = ((const float4*)x)[2 * i];
        float4 b = ((const float4*)x)[2 * i + 1];
        float v[8] = {a.x, a.y, a.z, a.w, b.x, b.y, b.z, b.w};
        unsigned short hi[8], lo[8];
#pragma unroll
        for (int j = 0; j < 8; j++) {
            hi[j] = f2bf(v[j]);
            lo[j] = f2bf(v[j] - bf2f(hi[j]));
        }
        *(uint4*)(xh + (size_t)i * 8) = *(const uint4*)hi;
        *(uint4*)(xl + (size_t)i * 8) = *(const uint4*)lo;
    }
}

// ---------------- Wr1 -> wcat [DQ][3*D]: [W_hi^T | W_lo^T | W_hi^T] -------------
__global__ void wsplit_kernel(const float* __restrict__ W, unsigned short* __restrict__ wcat) {
    __shared__ float tile[32][33];
    int tx = threadIdx.x, ty = threadIdx.y;          // 32 x 8
    int n0 = blockIdx.x * 32, k0 = blockIdx.y * 32;
#pragma unroll
    for (int j = 0; j < 4; j++)
        tile[ty + j * 8][tx] = W[(size_t)(k0 + ty + j * 8) * DQ_ + n0 + tx];   // tile[k][n]
    __syncthreads();
#pragma unroll
    for (int j = 0; j < 4; j++) {
        float v = tile[tx][ty + j * 8];              // k = k0+tx, n = n0+ty+j*8
        unsigned short hi = f2bf(v);
        unsigned short lo = f2bf(v - bf2f(hi));
        size_t row = (size_t)(n0 + ty + j * 8) * (3 * D_);
        wcat[row + k0 + tx]            = hi;
        wcat[row + D_ + k0 + tx]       = lo;
        wcat[row + 2 * D_ + k0 + tx]   = hi;
    }
}

// ---------------- transpose + fp32->bf16 convert: out[c][r] = bf16(in[r][c]) ----
__global__ void transpose_bf16_kernel(const float* __restrict__ in,
                                      unsigned short* __restrict__ out,
                                      int R, int C) {
    __shared__ float tile[32][33];
    int tx = threadIdx.x, ty = threadIdx.y;       // 32 x 8
    int c0 = blockIdx.x * 32, r0 = blockIdx.y * 32;
#pragma unroll
    for (int j = 0; j < 4; j++)
        tile[ty + j * 8][tx] = in[(size_t)(r0 + ty + j * 8) * C + c0 + tx];
    __syncthreads();
#pragma unroll
    for (int j = 0; j < 4; j++)
        out[(size_t)(c0 + ty + j * 8) * R + r0 + tx] = f2bf(tile[tx][ty + j * 8]);
}

// ---------------- router GEMM on MFMA: H = relu(split-bf16(x @ Wr1) + br1) ------
// K = 3 segments of 2048: x_hi@W_hi + x_hi@W_lo + x_lo@W_hi, fp32 accum
__global__ __launch_bounds__(256) void router_mfma(const unsigned short* __restrict__ xh,
                                                   const unsigned short* __restrict__ xl,
                                                   const unsigned short* __restrict__ wcat,
                                                   const float* __restrict__ bias,
                                                   float* __restrict__ H) {
    __shared__ unsigned short As[128 * 32];
    __shared__ unsigned short Bs[128 * 32];
    const int t = threadIdx.x;
    const int w = t >> 6, l = t & 63;
    const int m0 = blockIdx.y * 128, n0 = blockIdx.x * 128;
    const int wm = (w >> 1) * 64, wn = (w & 1) * 64;

    f32x4 acc[4][4];
    const f32x4 z = {0.f, 0.f, 0.f, 0.f};
#pragma unroll
    for (int i = 0; i < 4; i++)
#pragma unroll
        for (int j = 0; j < 4; j++) acc[i][j] = z;

    const int ra = t >> 2;
    const int ca = (t & 3) * 8;
    char* lA = (char*)As + w * 1024;
    char* lB = (char*)Bs + w * 1024;

    for (int seg = 0; seg < 3; seg++) {
        const unsigned short* Aseg = (seg == 2) ? xl : xh;
        const unsigned short* gA0 = Aseg + (size_t)(m0 + ra) * D_ + ca;
        const unsigned short* gA1 = Aseg + (size_t)(m0 + 64 + ra) * D_ + ca;
        const unsigned short* gB0 = wcat + (size_t)(n0 + ra) * (3 * D_) + seg * D_ + ca;
        const unsigned short* gB1 = wcat + (size_t)(n0 + 64 + ra) * (3 * D_) + seg * D_ + ca;
        for (int k0 = 0; k0 < D_; k0 += 32) {
            gload16(gA0 + k0, lA);
            gload16(gA1 + k0, lA + 4096);
            gload16(gB0 + k0, lB);
            gload16(gB1 + k0, lB + 4096);
            __syncthreads();
            bf16x8 af[4], bb[4];
#pragma unroll
            for (int i = 0; i < 4; i++) {
                af[i] = *(const bf16x8*)(As + (wm + i * 16 + (l & 15)) * 32 + (l >> 4) * 8);
                bb[i] = *(const bf16x8*)(Bs + (wn + i * 16 + (l & 15)) * 32 + (l >> 4) * 8);
            }
#pragma unroll
            for (int i = 0; i < 4; i++)
#pragma unroll
                for (int j = 0; j < 4; j++)
                    acc[i][j] = __builtin_amdgcn_mfma_f32_16x16x32_bf16(af[i], bb[j], acc[i][j], 0, 0, 0);
            __syncthreads();
        }
    }
#pragma unroll
    for (int i = 0; i < 4; i++) {
        int mbase = m0 + wm + i * 16 + (l >> 4) * 4;
#pragma unroll
        for (int j = 0; j < 4; j++) {
            int n = n0 + wn + j * 16 + (l & 15);
            float bv = bias[n];
#pragma unroll
            for (int q = 0; q < 4; q++)
                H[(size_t)(mbase + q) * DQ_ + n] = fmaxf(acc[i][j][q] + bv, 0.f);
        }
    }
}

// ---------------- scores = H @ Wr2 + br2 (one wave per token) -------------------
__global__ void score_kernel(const float* __restrict__ H, const float* __restrict__ Wr2,
                             const float* __restrict__ br2, float* __restrict__ scores) {
    int wv = threadIdx.x >> 6, l = threadIdx.x & 63;
    int tok = blockIdx.x * 4 + wv;
    const float* hrow = H + (size_t)tok * DQ_;
    float4 a0 = ((const float4*)hrow)[l];
    float4 a1 = ((const float4*)hrow)[64 + l];
    float4 w0 = ((const float4*)Wr2)[l];
    float4 w1 = ((const float4*)Wr2)[64 + l];
    float s = a0.x * w0.x + a0.y * w0.y + a0.z * w0.z + a0.w * w0.w
            + a1.x * w1.x + a1.y * w1.y + a1.z * w1.z + a1.w * w1.w;
#pragma unroll
    for (int off = 32; off >= 1; off >>= 1) s += __shfl_xor(s, off);
    if (l == 0) scores[tok] = s + br2[0];
}

// ---------------- exact top-k per batch row (bitonic sort, 4096 keys) -----------
__global__ __launch_bounds__(1024) void topk_kernel(const float* __restrict__ scores,
                                                    int* __restrict__ sel_idx,
                                                    float* __restrict__ maskF) {
    __shared__ unsigned long long keys[S_];
    __shared__ unsigned char flags[S_];
    int b = blockIdx.x, t = threadIdx.x;                       // 1024 threads
    for (int i = t; i < S_; i += 1024) {
        float f = scores[b * S_ + i];
        unsigned u = __float_as_uint(f);
        u = (u & 0x80000000u) ? ~u : (u | 0x80000000u);
        keys[i] = ((unsigned long long)u << 32) | (unsigned)(S_ - 1 - i);
        flags[i] = 0;
    }
    __syncthreads();
    for (int k = 2; k <= S_; k <<= 1)
        for (int j = k >> 1; j > 0; j >>= 1) {
            for (int i = t; i < S_; i += 1024) {
                int l = i ^ j;
                if (l > i) {
                    unsigned long long a = keys[i], c = keys[l];
                    bool up = ((i & k) == 0);
                    if (up ? (a > c) : (a < c)) { keys[i] = c; keys[l] = a; }
                }
            }
            __syncthreads();
        }
    for (int i = t; i < KSEL_; i += 1024) {
        unsigned long long kk = keys[S_ - KSEL_ + i];
        int s = (S_ - 1) - (int)(kk & 0xFFFFFFFFu);
        sel_idx[b * KSEL_ + i] = s;
        flags[s] = 1;
    }
    __syncthreads();
    for (int i = t; i < S_; i += 1024)
        maskF[b * S_ + i] = flags[i] ? 1.0f : 0.0f;
}

// ---------------- gather selected rows, convert to bf16 -------------------------
__global__ void gather_kernel(const float* __restrict__ x, const int* __restrict__ sel_idx,
                              unsigned short* __restrict__ sel) {
    int jrow = blockIdx.x;               // 0..2047
    int b = jrow >> 9;
    int tok = sel_idx[jrow];
    const float* src = x + ((size_t)(b * S_ + tok)) * D_;
    int t = threadIdx.x;                 // 256
    float4 v0 = ((const float4*)src)[2 * t];
    float4 v1 = ((const float4*)src)[2 * t + 1];
    unsigned p0 = (unsigned)f2bf(v0.x) | ((unsigned)f2bf(v0.y) << 16);
    unsigned p1 = (unsigned)f2bf(v0.z) | ((unsigned)f2bf(v0.w) << 16);
    unsigned p2 = (unsigned)f2bf(v1.x) | ((unsigned)f2bf(v1.y) << 16);
    unsigned p3 = (unsigned)f2bf(v1.z) | ((unsigned)f2bf(v1.w) << 16);
    *(uint4*)(sel + (size_t)jrow * D_ + t * 8) = make_uint4(p0, p1, p2, p3);
}

// ---------------- plain copy x -> out --------------------------------------------
__global__ void copy_kernel(const float4* __restrict__ src, float4* __restrict__ dst, int n4) {
    int i = blockIdx.x * blockDim.x + threadIdx.x;
    int stride = gridDim.x * blockDim.x;
    for (; i < n4; i += stride) dst[i] = src[i];
}

// ---------------- bf16 MFMA GEMM, m97 structure (128x128 tile, BK=32) -----------
__global__ __launch_bounds__(256) void mfma_gemm(const unsigned short* __restrict__ A,
                                                 const unsigned short* __restrict__ Bt,
                                                 int M, int N, int K,
                                                 const float* __restrict__ bias,
                                                 unsigned short* __restrict__ Cbf,
                                                 float* __restrict__ outF,
                                                 const int* __restrict__ sel_idx,
                                                 int epi) {
    __shared__ unsigned short As[128 * 32];
    __shared__ unsigned short Bs[128 * 32];
    const int t = threadIdx.x;
    const int w = t >> 6, l = t & 63;
    const int m0 = blockIdx.y * 128, n0 = blockIdx.x * 128;
    const int wm = (w >> 1) * 64, wn = (w & 1) * 64;

    f32x4 acc[4][4];
    const f32x4 z = {0.f, 0.f, 0.f, 0.f};
#pragma unroll
    for (int i = 0; i < 4; i++)
#pragma unroll
        for (int j = 0; j < 4; j++) acc[i][j] = z;

    const int ra = t >> 2;
    const int ca = (t & 3) * 8;
    const unsigned short* gA0 = A + (size_t)(m0 + ra) * K + ca;
    const unsigned short* gA1 = A + (size_t)(m0 + 64 + ra) * K + ca;
    const unsigned short* gB0 = Bt + (size_t)(n0 + ra) * K + ca;
    const unsigned short* gB1 = Bt + (size_t)(n0 + 64 + ra) * K + ca;
    char* lA = (char*)As + w * 1024;
    char* lB = (char*)Bs + w * 1024;

    for (int k0 = 0; k0 < K; k0 += 32) {
        gload16(gA0 + k0, lA);
        gload16(gA1 + k0, lA + 4096);
        gload16(gB0 + k0, lB);
        gload16(gB1 + k0, lB + 4096);
        __syncthreads();
        bf16x8 af[4], bb[4];
#pragma unroll
        for (int i = 0; i < 4; i++) {
            af[i] = *(const bf16x8*)(As + (wm + i * 16 + (l & 15)) * 32 + (l >> 4) * 8);
            bb[i] = *(const bf16x8*)(Bs + (wn + i * 16 + (l & 15)) * 32 + (l >> 4) * 8);
        }
#pragma unroll
        for (int i = 0; i < 4; i++)
#pragma unroll
            for (int j = 0; j < 4; j++)
                acc[i][j] = __builtin_amdgcn_mfma_f32_16x16x32_bf16(af[i], bb[j], acc[i][j], 0, 0, 0);
        __syncthreads();
    }

    if (epi == 0) {
#pragma unroll
        for (int i = 0; i < 4; i++) {
            int mbase = m0 + wm + i * 16 + (l >> 4) * 4;
#pragma unroll
            for (int j = 0; j < 4; j++) {
                int n = n0 + wn + j * 16 + (l & 15);
                float bv = bias[n];
#pragma unroll
                for (int q = 0; q < 4; q++) {
                    float v = acc[i][j][q] + bv;
                    v = fmaxf(v, 0.f);
                    Cbf[(size_t)(mbase + q) * N + n] = f2bf(v);
                }
            }
        }
    } else {
#pragma unroll
        for (int i = 0; i < 4; i++) {
            int mbase = m0 + wm + i * 16 + (l >> 4) * 4;
#pragma unroll
            for (int q = 0; q < 4; q++) {
                int m = mbase + q;
                int brow = m >> 9;
                int tok = sel_idx[m];
                float* orow = outF + ((size_t)(brow * S_ + tok)) * D_;
#pragma unroll
                for (int j = 0; j < 4; j++) {
                    int n = n0 + wn + j * 16 + (l & 15);
                    orow[n] = acc[i][j][q] + bias[n];
                }
            }
        }
    }
}

extern "C" void kernel_launch(void* const* d_in, const int* in_sizes, int n_in,
                              void* d_out, int out_size, void* d_ws, size_t ws_size,
                              hipStream_t stream) {
    const float* x   = (const float*)d_in[0];
    const float* Wr1 = (const float*)d_in[1];
    const float* br1 = (const float*)d_in[2];
    const float* Wr2 = (const float*)d_in[3];
    const float* br2 = (const float*)d_in[4];
    const float* Wf1 = (const float*)d_in[5];
    const float* bf1 = (const float*)d_in[6];
    const float* Wf2 = (const float*)d_in[7];
    const float* bf2 = (const float*)d_in[8];
    float* out = (float*)d_out;
    char* ws = (char*)d_ws;

    // ---- workspace layout (phase-overlapped) ----
    // phase 1 (router):   xh 0..64M | xl 64..128M | h 128..160M | wcat 160..166M
    // phase 2 (FFN):      w1t 0..32M | w2t 32..64M | h1 64..96M | sel 96..104M
    unsigned short* xh   = (unsigned short*)(ws);
    unsigned short* xl   = (unsigned short*)(ws + 67108864);
    float* h             = (float*)(ws + 134217728);
    unsigned short* wcat = (unsigned short*)(ws + 167772160);
    float* scores        = (float*)(ws + 174063616);
    int* sel_idx         = (int*)(ws + 174129152);
    unsigned short* w1t  = (unsigned short*)(ws);
    unsigned short* w2t  = (unsigned short*)(ws + 33554432);
    unsigned short* h1   = (unsigned short*)(ws + 67108864);
    unsigned short* sel  = (unsigned short*)(ws + 100663296);
    float* maskF         = out + (size_t)B_ * S_ * D_;

    (void)in_sizes; (void)n_in; (void)out_size; (void)ws_size;

    // 1. split x into bf16 hi/lo
    split_x_kernel<<<2048, 256, 0, stream>>>(x, xh, xl, (M_ * D_) / 8);
    // 2. Wr1 -> [W_hi^T | W_lo^T | W_hi^T]
    wsplit_kernel<<<dim3(DQ_ / 32, D_ / 32), dim3(32, 8), 0, stream>>>(Wr1, wcat);
    // 3. router hidden via bf16 MFMA (split precision, fp32 accum)
    router_mfma<<<dim3(DQ_ / 128, M_ / 128), 256, 0, stream>>>(xh, xl, wcat, br1, h);
    // 4. scores
    score_kernel<<<M_ / 4, 256, 0, stream>>>(h, Wr2, br2, scores);
    // 5. exact top-k + mask
    topk_kernel<<<B_, 1024, 0, stream>>>(scores, sel_idx, maskF);
    // 6. gather selected tokens -> bf16 (overwrites dead xl region)
    gather_kernel<<<B_ * KSEL_, 256, 0, stream>>>(x, sel_idx, sel);
    // 7. FFN weight transpose + bf16 convert (overwrites dead xh region)
    transpose_bf16_kernel<<<dim3(DF_ / 32, D_ / 32), dim3(32, 8), 0, stream>>>(Wf1, w1t, D_, DF_);
    transpose_bf16_kernel<<<dim3(D_ / 32, DF_ / 32), dim3(32, 8), 0, stream>>>(Wf2, w2t, DF_, D_);
    // 8. copy x -> out
    copy_kernel<<<2048, 256, 0, stream>>>((const float4*)x, (float4*)out,
                                          (B_ * S_ * D_) / 4);
    // 9. FFN gemm1: h1 = bf16(relu(sel @ Wf1 + bf1))
    mfma_gemm<<<dim3(DF_ / 128, (B_ * KSEL_) / 128), 256, 0, stream>>>(
        sel, w1t, B_ * KSEL_, DF_, D_, bf1, h1, nullptr, nullptr, 0);
    // 10. FFN gemm2 + scatter
    mfma_gemm<<<dim3(D_ / 128, (B_ * KSEL_) / 128), 256, 0, stream>>>(
        h1, w2t, B_ * KSEL_, D_, DF_, bf2, nullptr, out, sel_idx, 1);
}

// Round 3
// 605.414 us; speedup vs baseline: 1.7016x; 1.1501x over previous
//
#include <hip/hip_runtime.h>

#define B_    4
#define S_    4096
#define D_    2048
#define DQ_   512
#define DF_   8192
#define KSEL_ 512
#define M_    (B_ * S_)     // 16384
#define MS_   (B_ * KSEL_)  // 2048 selected rows

typedef __attribute__((ext_vector_type(8))) short bf16x8;
typedef __attribute__((ext_vector_type(4))) float f32x4;
typedef __attribute__((address_space(3))) void as3_void;
typedef const __attribute__((address_space(1))) void as1_cvoid;

__device__ __forceinline__ unsigned short f2bf(float f) {
    unsigned u = __float_as_uint(f);
    u += 0x7FFFu + ((u >> 16) & 1u);   // RNE
    return (unsigned short)(u >> 16);
}
__device__ __forceinline__ float bf2f(unsigned short h) {
    return __uint_as_float(((unsigned)h) << 16);
}

__device__ __forceinline__ void gload16(const void* g, void* l) {
    __builtin_amdgcn_global_load_lds((as1_cvoid*)g, (as3_void*)l, 16, 0, 0);
}

// ---------------- split x into bf16 hi/lo AND copy x -> out ---------------------
__global__ void split_copy_kernel(const float* __restrict__ x,
                                  unsigned short* __restrict__ xh,
                                  unsigned short* __restrict__ xl,
                                  float* __restrict__ out, int n8) {
    int i = blockIdx.x * blockDim.x + threadIdx.x;
    int stride = gridDim.x * blockDim.x;
    for (; i < n8; i += stride) {
        float4 a = ((const float4*)x)[2 * i];
        float4 b = ((const float4*)x)[2 * i + 1];
        ((float4*)out)[2 * i]     = a;
        ((float4*)out)[2 * i + 1] = b;
        float v[8] = {a.x, a.y, a.z, a.w, b.x, b.y, b.z, b.w};
        unsigned short hi[8], lo[8];
#pragma unroll
        for (int j = 0; j < 8; j++) {
            hi[j] = f2bf(v[j]);
            lo[j] = f2bf(v[j] - bf2f(hi[j]));
        }
        *(uint4*)(xh + (size_t)i * 8) = *(const uint4*)hi;
        *(uint4*)(xl + (size_t)i * 8) = *(const uint4*)lo;
    }
}

// ---------------- Wr1 -> wcat [DQ][3*D]: [W_hi^T | W_lo^T | W_hi^T] -------------
__global__ void wsplit_kernel(const float* __restrict__ W, unsigned short* __restrict__ wcat) {
    __shared__ float tile[32][33];
    int tx = threadIdx.x, ty = threadIdx.y;          // 32 x 8
    int n0 = blockIdx.x * 32, k0 = blockIdx.y * 32;
#pragma unroll
    for (int j = 0; j < 4; j++)
        tile[ty + j * 8][tx] = W[(size_t)(k0 + ty + j * 8) * DQ_ + n0 + tx];   // tile[k][n]
    __syncthreads();
#pragma unroll
    for (int j = 0; j < 4; j++) {
        float v = tile[tx][ty + j * 8];              // k = k0+tx, n = n0+ty+j*8
        unsigned short hi = f2bf(v);
        unsigned short lo = f2bf(v - bf2f(hi));
        size_t row = (size_t)(n0 + ty + j * 8) * (3 * D_);
        wcat[row + k0 + tx]            = hi;
        wcat[row + D_ + k0 + tx]       = lo;
        wcat[row + 2 * D_ + k0 + tx]   = hi;
    }
}

// ---------------- transpose + fp32->bf16 convert: out[c][r] = bf16(in[r][c]) ----
__global__ void transpose_bf16_kernel(const float* __restrict__ in,
                                      unsigned short* __restrict__ out,
                                      int R, int C) {
    __shared__ float tile[32][33];
    int tx = threadIdx.x, ty = threadIdx.y;       // 32 x 8
    int c0 = blockIdx.x * 32, r0 = blockIdx.y * 32;
#pragma unroll
    for (int j = 0; j < 4; j++)
        tile[ty + j * 8][tx] = in[(size_t)(r0 + ty + j * 8) * C + c0 + tx];
    __syncthreads();
#pragma unroll
    for (int j = 0; j < 4; j++)
        out[(size_t)(c0 + ty + j * 8) * R + r0 + tx] = f2bf(tile[tx][ty + j * 8]);
}

// ---------------- router GEMM on MFMA: H = relu(split-bf16(x @ Wr1) + br1) ------
// K = 3 segments of 2048: x_hi@W_hi + x_hi@W_lo + x_lo@W_hi, fp32 accum
__global__ __launch_bounds__(256) void router_mfma(const unsigned short* __restrict__ xh,
                                                   const unsigned short* __restrict__ xl,
                                                   const unsigned short* __restrict__ wcat,
                                                   const float* __restrict__ bias,
                                                   float* __restrict__ H) {
    __shared__ unsigned short As[128 * 32];
    __shared__ unsigned short Bs[128 * 32];
    const int t = threadIdx.x;
    const int w = t >> 6, l = t & 63;
    const int m0 = blockIdx.y * 128, n0 = blockIdx.x * 128;
    const int wm = (w >> 1) * 64, wn = (w & 1) * 64;

    f32x4 acc[4][4];
    const f32x4 z = {0.f, 0.f, 0.f, 0.f};
#pragma unroll
    for (int i = 0; i < 4; i++)
#pragma unroll
        for (int j = 0; j < 4; j++) acc[i][j] = z;

    const int ra = t >> 2;
    const int ca = (t & 3) * 8;
    char* lA = (char*)As + w * 1024;
    char* lB = (char*)Bs + w * 1024;

    for (int seg = 0; seg < 3; seg++) {
        const unsigned short* Aseg = (seg == 2) ? xl : xh;
        const unsigned short* gA0 = Aseg + (size_t)(m0 + ra) * D_ + ca;
        const unsigned short* gA1 = Aseg + (size_t)(m0 + 64 + ra) * D_ + ca;
        const unsigned short* gB0 = wcat + (size_t)(n0 + ra) * (3 * D_) + seg * D_ + ca;
        const unsigned short* gB1 = wcat + (size_t)(n0 + 64 + ra) * (3 * D_) + seg * D_ + ca;
        for (int k0 = 0; k0 < D_; k0 += 32) {
            gload16(gA0 + k0, lA);
            gload16(gA1 + k0, lA + 4096);
            gload16(gB0 + k0, lB);
            gload16(gB1 + k0, lB + 4096);
            __syncthreads();
            bf16x8 af[4], bb[4];
#pragma unroll
            for (int i = 0; i < 4; i++) {
                af[i] = *(const bf16x8*)(As + (wm + i * 16 + (l & 15)) * 32 + (l >> 4) * 8);
                bb[i] = *(const bf16x8*)(Bs + (wn + i * 16 + (l & 15)) * 32 + (l >> 4) * 8);
            }
#pragma unroll
            for (int i = 0; i < 4; i++)
#pragma unroll
                for (int j = 0; j < 4; j++)
                    acc[i][j] = __builtin_amdgcn_mfma_f32_16x16x32_bf16(af[i], bb[j], acc[i][j], 0, 0, 0);
            __syncthreads();
        }
    }
#pragma unroll
    for (int i = 0; i < 4; i++) {
        int mbase = m0 + wm + i * 16 + (l >> 4) * 4;
#pragma unroll
        for (int j = 0; j < 4; j++) {
            int n = n0 + wn + j * 16 + (l & 15);
            float bv = bias[n];
#pragma unroll
            for (int q = 0; q < 4; q++)
                H[(size_t)(mbase + q) * DQ_ + n] = fmaxf(acc[i][j][q] + bv, 0.f);
        }
    }
}

// ---------------- scores = H @ Wr2 + br2 (one wave per token) -------------------
__global__ void score_kernel(const float* __restrict__ H, const float* __restrict__ Wr2,
                             const float* __restrict__ br2, float* __restrict__ scores) {
    int wv = threadIdx.x >> 6, l = threadIdx.x & 63;
    int tok = blockIdx.x * 4 + wv;
    const float* hrow = H + (size_t)tok * DQ_;
    float4 a0 = ((const float4*)hrow)[l];
    float4 a1 = ((const float4*)hrow)[64 + l];
    float4 w0 = ((const float4*)Wr2)[l];
    float4 w1 = ((const float4*)Wr2)[64 + l];
    float s = a0.x * w0.x + a0.y * w0.y + a0.z * w0.z + a0.w * w0.w
            + a1.x * w1.x + a1.y * w1.y + a1.z * w1.z + a1.w * w1.w;
#pragma unroll
    for (int off = 32; off >= 1; off >>= 1) s += __shfl_xor(s, off);
    if (l == 0) scores[tok] = s + br2[0];
}

// ---------------- exact top-k per batch row (bitonic sort, 4096 keys) -----------
__global__ __launch_bounds__(1024) void topk_kernel(const float* __restrict__ scores,
                                                    int* __restrict__ sel_idx,
                                                    float* __restrict__ maskF) {
    __shared__ unsigned long long keys[S_];
    __shared__ unsigned char flags[S_];
    int b = blockIdx.x, t = threadIdx.x;                       // 1024 threads
    for (int i = t; i < S_; i += 1024) {
        float f = scores[b * S_ + i];
        unsigned u = __float_as_uint(f);
        u = (u & 0x80000000u) ? ~u : (u | 0x80000000u);
        keys[i] = ((unsigned long long)u << 32) | (unsigned)(S_ - 1 - i);
        flags[i] = 0;
    }
    __syncthreads();
    for (int k = 2; k <= S_; k <<= 1)
        for (int j = k >> 1; j > 0; j >>= 1) {
            for (int i = t; i < S_; i += 1024) {
                int l = i ^ j;
                if (l > i) {
                    unsigned long long a = keys[i], c = keys[l];
                    bool up = ((i & k) == 0);
                    if (up ? (a > c) : (a < c)) { keys[i] = c; keys[l] = a; }
                }
            }
            __syncthreads();
        }
    for (int i = t; i < KSEL_; i += 1024) {
        unsigned long long kk = keys[S_ - KSEL_ + i];
        int s = (S_ - 1) - (int)(kk & 0xFFFFFFFFu);
        sel_idx[b * KSEL_ + i] = s;
        flags[s] = 1;
    }
    __syncthreads();
    for (int i = t; i < S_; i += 1024)
        maskF[b * S_ + i] = flags[i] ? 1.0f : 0.0f;
}

// ---------------- gather selected rows, convert to bf16 -------------------------
__global__ void gather_kernel(const float* __restrict__ x, const int* __restrict__ sel_idx,
                              unsigned short* __restrict__ sel) {
    int jrow = blockIdx.x;               // 0..2047
    int b = jrow >> 9;
    int tok = sel_idx[jrow];
    const float* src = x + ((size_t)(b * S_ + tok)) * D_;
    int t = threadIdx.x;                 // 256
    float4 v0 = ((const float4*)src)[2 * t];
    float4 v1 = ((const float4*)src)[2 * t + 1];
    unsigned p0 = (unsigned)f2bf(v0.x) | ((unsigned)f2bf(v0.y) << 16);
    unsigned p1 = (unsigned)f2bf(v0.z) | ((unsigned)f2bf(v0.w) << 16);
    unsigned p2 = (unsigned)f2bf(v1.x) | ((unsigned)f2bf(v1.y) << 16);
    unsigned p3 = (unsigned)f2bf(v1.z) | ((unsigned)f2bf(v1.w) << 16);
    *(uint4*)(sel + (size_t)jrow * D_ + t * 8) = make_uint4(p0, p1, p2, p3);
}

// ---------------- bf16 MFMA GEMM, m97 structure, optional split-K ---------------
// A [M][K] bf16 row-major, Bt [N][K] bf16 row-major. Block computes K range
// [blockIdx.z*kspan, +kspan).
// epi==0: C = bf16(relu(acc + bias[n])) -> Cbf [M][N]
// epi==2: partial[blockIdx.z*M*N + m*N + n] = acc (fp32, no bias)
__global__ __launch_bounds__(256) void mfma_gemm(const unsigned short* __restrict__ A,
                                                 const unsigned short* __restrict__ Bt,
                                                 int M, int N, int K, int kspan,
                                                 const float* __restrict__ bias,
                                                 unsigned short* __restrict__ Cbf,
                                                 float* __restrict__ partial,
                                                 int epi) {
    __shared__ unsigned short As[128 * 32];
    __shared__ unsigned short Bs[128 * 32];
    const int t = threadIdx.x;
    const int w = t >> 6, l = t & 63;
    const int m0 = blockIdx.y * 128, n0 = blockIdx.x * 128;
    const int wm = (w >> 1) * 64, wn = (w & 1) * 64;
    const int kbeg = blockIdx.z * kspan;

    f32x4 acc[4][4];
    const f32x4 z = {0.f, 0.f, 0.f, 0.f};
#pragma unroll
    for (int i = 0; i < 4; i++)
#pragma unroll
        for (int j = 0; j < 4; j++) acc[i][j] = z;

    const int ra = t >> 2;
    const int ca = (t & 3) * 8;
    const unsigned short* gA0 = A + (size_t)(m0 + ra) * K + ca + kbeg;
    const unsigned short* gA1 = A + (size_t)(m0 + 64 + ra) * K + ca + kbeg;
    const unsigned short* gB0 = Bt + (size_t)(n0 + ra) * K + ca + kbeg;
    const unsigned short* gB1 = Bt + (size_t)(n0 + 64 + ra) * K + ca + kbeg;
    char* lA = (char*)As + w * 1024;
    char* lB = (char*)Bs + w * 1024;

    for (int k0 = 0; k0 < kspan; k0 += 32) {
        gload16(gA0 + k0, lA);
        gload16(gA1 + k0, lA + 4096);
        gload16(gB0 + k0, lB);
        gload16(gB1 + k0, lB + 4096);
        __syncthreads();
        bf16x8 af[4], bb[4];
#pragma unroll
        for (int i = 0; i < 4; i++) {
            af[i] = *(const bf16x8*)(As + (wm + i * 16 + (l & 15)) * 32 + (l >> 4) * 8);
            bb[i] = *(const bf16x8*)(Bs + (wn + i * 16 + (l & 15)) * 32 + (l >> 4) * 8);
        }
#pragma unroll
        for (int i = 0; i < 4; i++)
#pragma unroll
            for (int j = 0; j < 4; j++)
                acc[i][j] = __builtin_amdgcn_mfma_f32_16x16x32_bf16(af[i], bb[j], acc[i][j], 0, 0, 0);
        __syncthreads();
    }

    if (epi == 0) {
#pragma unroll
        for (int i = 0; i < 4; i++) {
            int mbase = m0 + wm + i * 16 + (l >> 4) * 4;
#pragma unroll
            for (int j = 0; j < 4; j++) {
                int n = n0 + wn + j * 16 + (l & 15);
                float bv = bias[n];
#pragma unroll
                for (int q = 0; q < 4; q++) {
                    float v = acc[i][j][q] + bv;
                    v = fmaxf(v, 0.f);
                    Cbf[(size_t)(mbase + q) * N + n] = f2bf(v);
                }
            }
        }
    } else {
        float* pseg = partial + (size_t)blockIdx.z * M * N;
#pragma unroll
        for (int i = 0; i < 4; i++) {
            int mbase = m0 + wm + i * 16 + (l >> 4) * 4;
#pragma unroll
            for (int j = 0; j < 4; j++) {
                int n = n0 + wn + j * 16 + (l & 15);
#pragma unroll
                for (int q = 0; q < 4; q++)
                    pseg[(size_t)(mbase + q) * N + n] = acc[i][j][q];
            }
        }
    }
}

// ---------------- sum 4 split-K partials + bias, scatter to out rows ------------
__global__ void reduce_scatter_kernel(const float* __restrict__ partial,
                                      const float* __restrict__ bias,
                                      const int* __restrict__ sel_idx,
                                      float* __restrict__ out) {
    int m = blockIdx.x;                  // 0..2047
    int t = threadIdx.x;                 // 256
    int brow = m >> 9;
    int tok = sel_idx[m];
    float* orow = out + ((size_t)(brow * S_ + tok)) * D_;
    const float* p0 = partial + (size_t)m * D_;
    const size_t seg = (size_t)MS_ * D_;
#pragma unroll
    for (int r = 0; r < 2; r++) {
        int c = (t + r * 256) * 4;
        float4 v0 = *(const float4*)(p0 + c);
        float4 v1 = *(const float4*)(p0 + seg + c);
        float4 v2 = *(const float4*)(p0 + 2 * seg + c);
        float4 v3 = *(const float4*)(p0 + 3 * seg + c);
        float4 bv = *(const float4*)(bias + c);
        float4 o;
        o.x = v0.x + v1.x + v2.x + v3.x + bv.x;
        o.y = v0.y + v1.y + v2.y + v3.y + bv.y;
        o.z = v0.z + v1.z + v2.z + v3.z + bv.z;
        o.w = v0.w + v1.w + v2.w + v3.w + bv.w;
        *(float4*)(orow + c) = o;
    }
}

extern "C" void kernel_launch(void* const* d_in, const int* in_sizes, int n_in,
                              void* d_out, int out_size, void* d_ws, size_t ws_size,
                              hipStream_t stream) {
    const float* x   = (const float*)d_in[0];
    const float* Wr1 = (const float*)d_in[1];
    const float* br1 = (const float*)d_in[2];
    const float* Wr2 = (const float*)d_in[3];
    const float* br2 = (const float*)d_in[4];
    const float* Wf1 = (const float*)d_in[5];
    const float* bf1 = (const float*)d_in[6];
    const float* Wf2 = (const float*)d_in[7];
    const float* bf2 = (const float*)d_in[8];
    float* out = (float*)d_out;
    char* ws = (char*)d_ws;

    // ---- workspace layout (MiB offsets, phase-overlapped) ----
    // phase 1 (router): xh 0-64 | xl 64-128 | h 128-160 | wcat 160-166 | scores 168 | sel_idx 169
    // phase 2 (FFN):    partial 0-64 | w1t 64-96 | w2t 96-128 | h1 128-160 | sel 160-168
    unsigned short* xh   = (unsigned short*)(ws);
    unsigned short* xl   = (unsigned short*)(ws + (64u << 20));
    float* h             = (float*)(ws + (128u << 20));
    unsigned short* wcat = (unsigned short*)(ws + (160u << 20));
    float* scores        = (float*)(ws + (168u << 20));
    int* sel_idx         = (int*)(ws + (169u << 20));
    float* partial       = (float*)(ws);
    unsigned short* w1t  = (unsigned short*)(ws + (64u << 20));
    unsigned short* w2t  = (unsigned short*)(ws + (96u << 20));
    unsigned short* h1   = (unsigned short*)(ws + (128u << 20));
    unsigned short* sel  = (unsigned short*)(ws + (160u << 20));
    float* maskF         = out + (size_t)B_ * S_ * D_;

    (void)in_sizes; (void)n_in; (void)out_size; (void)ws_size;

    // 1. split x into bf16 hi/lo + copy x -> out
    split_copy_kernel<<<2048, 256, 0, stream>>>(x, xh, xl, out, (M_ * D_) / 8);
    // 2. Wr1 -> [W_hi^T | W_lo^T | W_hi^T]
    wsplit_kernel<<<dim3(DQ_ / 32, D_ / 32), dim3(32, 8), 0, stream>>>(Wr1, wcat);
    // 3. router hidden via bf16 MFMA (split precision, fp32 accum)
    router_mfma<<<dim3(DQ_ / 128, M_ / 128), 256, 0, stream>>>(xh, xl, wcat, br1, h);
    // 4. scores
    score_kernel<<<M_ / 4, 256, 0, stream>>>(h, Wr2, br2, scores);
    // 5. exact top-k + mask
    topk_kernel<<<B_, 1024, 0, stream>>>(scores, sel_idx, maskF);
    // 6. gather selected tokens -> bf16
    gather_kernel<<<MS_, 256, 0, stream>>>(x, sel_idx, sel);
    // 7. FFN weight transpose + bf16 convert
    transpose_bf16_kernel<<<dim3(DF_ / 32, D_ / 32), dim3(32, 8), 0, stream>>>(Wf1, w1t, D_, DF_);
    transpose_bf16_kernel<<<dim3(D_ / 32, DF_ / 32), dim3(32, 8), 0, stream>>>(Wf2, w2t, DF_, D_);
    // 8. FFN gemm1: h1 = bf16(relu(sel @ Wf1 + bf1))   M=2048 N=8192 K=2048
    mfma_gemm<<<dim3(DF_ / 128, MS_ / 128, 1), 256, 0, stream>>>(
        sel, w1t, MS_, DF_, D_, D_, bf1, h1, nullptr, 0);
    // 9. FFN gemm2, split-K=4 -> fp32 partials   M=2048 N=2048 K=8192
    mfma_gemm<<<dim3(D_ / 128, MS_ / 128, 4), 256, 0, stream>>>(
        h1, w2t, MS_, D_, DF_, DF_ / 4, nullptr, nullptr, partial, 2);
    // 10. reduce partials + bias, scatter into out
    reduce_scatter_kernel<<<MS_, 256, 0, stream>>>(partial, bf2, sel_idx, out);
}

// Round 4
// 544.673 us; speedup vs baseline: 1.8914x; 1.1115x over previous
//
#include <hip/hip_runtime.h>

#define B_    4
#define S_    4096
#define D_    2048
#define DQ_   512
#define DF_   8192
#define KSEL_ 512
#define M_    (B_ * S_)     // 16384
#define MS_   (B_ * KSEL_)  // 2048 selected rows

typedef __attribute__((ext_vector_type(8))) short bf16x8;
typedef __attribute__((ext_vector_type(4))) float f32x4;
typedef __attribute__((address_space(3))) void as3_void;
typedef const __attribute__((address_space(1))) void as1_cvoid;

__device__ __forceinline__ unsigned short f2bf(float f) {
    unsigned u = __float_as_uint(f);
    u += 0x7FFFu + ((u >> 16) & 1u);   // RNE
    return (unsigned short)(u >> 16);
}
__device__ __forceinline__ float bf2f(unsigned short h) {
    return __uint_as_float(((unsigned)h) << 16);
}

__device__ __forceinline__ void gload16(const void* g, void* l) {
    __builtin_amdgcn_global_load_lds((as1_cvoid*)g, (as3_void*)l, 16, 0, 0);
}

// ---------------- split x into bf16 hi/lo AND copy x -> out ---------------------
__global__ void split_copy_kernel(const float* __restrict__ x,
                                  unsigned short* __restrict__ xh,
                                  unsigned short* __restrict__ xl,
                                  float* __restrict__ out, int n8) {
    int i = blockIdx.x * blockDim.x + threadIdx.x;
    int stride = gridDim.x * blockDim.x;
    for (; i < n8; i += stride) {
        float4 a = ((const float4*)x)[2 * i];
        float4 b = ((const float4*)x)[2 * i + 1];
        ((float4*)out)[2 * i]     = a;
        ((float4*)out)[2 * i + 1] = b;
        float v[8] = {a.x, a.y, a.z, a.w, b.x, b.y, b.z, b.w};
        unsigned short hi[8], lo[8];
#pragma unroll
        for (int j = 0; j < 8; j++) {
            hi[j] = f2bf(v[j]);
            lo[j] = f2bf(v[j] - bf2f(hi[j]));
        }
        *(uint4*)(xh + (size_t)i * 8) = *(const uint4*)hi;
        *(uint4*)(xl + (size_t)i * 8) = *(const uint4*)lo;
    }
}

// ---------------- Wr1 -> whiT [DQ][D], wloT [DQ][D] (bf16, transposed) ----------
__global__ void wsplit_kernel(const float* __restrict__ W,
                              unsigned short* __restrict__ whiT,
                              unsigned short* __restrict__ wloT) {
    __shared__ float tile[32][33];
    int tx = threadIdx.x, ty = threadIdx.y;          // 32 x 8
    int n0 = blockIdx.x * 32, k0 = blockIdx.y * 32;
#pragma unroll
    for (int j = 0; j < 4; j++)
        tile[ty + j * 8][tx] = W[(size_t)(k0 + ty + j * 8) * DQ_ + n0 + tx];   // tile[k][n]
    __syncthreads();
#pragma unroll
    for (int j = 0; j < 4; j++) {
        float v = tile[tx][ty + j * 8];              // k = k0+tx, n = n0+ty+j*8
        unsigned short hi = f2bf(v);
        unsigned short lo = f2bf(v - bf2f(hi));
        size_t row = (size_t)(n0 + ty + j * 8) * D_;
        whiT[row + k0 + tx] = hi;
        wloT[row + k0 + tx] = lo;
    }
}

// ---------------- transpose + fp32->bf16 convert: out[c][r] = bf16(in[r][c]) ----
__global__ void transpose_bf16_kernel(const float* __restrict__ in,
                                      unsigned short* __restrict__ out,
                                      int R, int C) {
    __shared__ float tile[32][33];
    int tx = threadIdx.x, ty = threadIdx.y;       // 32 x 8
    int c0 = blockIdx.x * 32, r0 = blockIdx.y * 32;
#pragma unroll
    for (int j = 0; j < 4; j++)
        tile[ty + j * 8][tx] = in[(size_t)(r0 + ty + j * 8) * C + c0 + tx];
    __syncthreads();
#pragma unroll
    for (int j = 0; j < 4; j++)
        out[(size_t)(c0 + ty + j * 8) * R + r0 + tx] = f2bf(tile[tx][ty + j * 8]);
}

// ---------------- fused router GEMM: acc += Ah*Bh + Ah*Bl + Al*Bh ---------------
// 48 MFMAs per barrier-pair; xh/xl each read once per block.
// grid (M/128, DQ/128): same-m n-blocks land on same XCD (ids differ by 128).
__global__ __launch_bounds__(256) void router_mfma(const unsigned short* __restrict__ xh,
                                                   const unsigned short* __restrict__ xl,
                                                   const unsigned short* __restrict__ whiT,
                                                   const unsigned short* __restrict__ wloT,
                                                   const float* __restrict__ bias,
                                                   float* __restrict__ H) {
    __shared__ unsigned short Ah[128 * 32];
    __shared__ unsigned short Al[128 * 32];
    __shared__ unsigned short Bh[128 * 32];
    __shared__ unsigned short Bl[128 * 32];
    const int t = threadIdx.x;
    const int w = t >> 6, l = t & 63;
    const int m0 = blockIdx.x * 128, n0 = blockIdx.y * 128;
    const int wm = (w >> 1) * 64, wn = (w & 1) * 64;

    f32x4 acc[4][4];
    const f32x4 z = {0.f, 0.f, 0.f, 0.f};
#pragma unroll
    for (int i = 0; i < 4; i++)
#pragma unroll
        for (int j = 0; j < 4; j++) acc[i][j] = z;

    const int ra = t >> 2;
    const int ca = (t & 3) * 8;
    const unsigned short* gAh0 = xh + (size_t)(m0 + ra) * D_ + ca;
    const unsigned short* gAh1 = xh + (size_t)(m0 + 64 + ra) * D_ + ca;
    const unsigned short* gAl0 = xl + (size_t)(m0 + ra) * D_ + ca;
    const unsigned short* gAl1 = xl + (size_t)(m0 + 64 + ra) * D_ + ca;
    const unsigned short* gBh0 = whiT + (size_t)(n0 + ra) * D_ + ca;
    const unsigned short* gBh1 = whiT + (size_t)(n0 + 64 + ra) * D_ + ca;
    const unsigned short* gBl0 = wloT + (size_t)(n0 + ra) * D_ + ca;
    const unsigned short* gBl1 = wloT + (size_t)(n0 + 64 + ra) * D_ + ca;
    char* lAh = (char*)Ah + w * 1024;
    char* lAl = (char*)Al + w * 1024;
    char* lBh = (char*)Bh + w * 1024;
    char* lBl = (char*)Bl + w * 1024;

    for (int k0 = 0; k0 < D_; k0 += 32) {
        gload16(gAh0 + k0, lAh);
        gload16(gAh1 + k0, lAh + 4096);
        gload16(gAl0 + k0, lAl);
        gload16(gAl1 + k0, lAl + 4096);
        gload16(gBh0 + k0, lBh);
        gload16(gBh1 + k0, lBh + 4096);
        gload16(gBl0 + k0, lBl);
        gload16(gBl1 + k0, lBl + 4096);
        __syncthreads();
        bf16x8 ah[4], al[4], bh[4], bl[4];
#pragma unroll
        for (int i = 0; i < 4; i++) {
            int ar = (wm + i * 16 + (l & 15)) * 32 + (l >> 4) * 8;
            int br = (wn + i * 16 + (l & 15)) * 32 + (l >> 4) * 8;
            ah[i] = *(const bf16x8*)(Ah + ar);
            al[i] = *(const bf16x8*)(Al + ar);
            bh[i] = *(const bf16x8*)(Bh + br);
            bl[i] = *(const bf16x8*)(Bl + br);
        }
#pragma unroll
        for (int i = 0; i < 4; i++)
#pragma unroll
            for (int j = 0; j < 4; j++) {
                acc[i][j] = __builtin_amdgcn_mfma_f32_16x16x32_bf16(ah[i], bh[j], acc[i][j], 0, 0, 0);
                acc[i][j] = __builtin_amdgcn_mfma_f32_16x16x32_bf16(ah[i], bl[j], acc[i][j], 0, 0, 0);
                acc[i][j] = __builtin_amdgcn_mfma_f32_16x16x32_bf16(al[i], bh[j], acc[i][j], 0, 0, 0);
            }
        __syncthreads();
    }
#pragma unroll
    for (int i = 0; i < 4; i++) {
        int mbase = m0 + wm + i * 16 + (l >> 4) * 4;
#pragma unroll
        for (int j = 0; j < 4; j++) {
            int n = n0 + wn + j * 16 + (l & 15);
            float bv = bias[n];
#pragma unroll
            for (int q = 0; q < 4; q++)
                H[(size_t)(mbase + q) * DQ_ + n] = fmaxf(acc[i][j][q] + bv, 0.f);
        }
    }
}

// ---------------- scores = H @ Wr2 + br2 (one wave per token) -------------------
__global__ void score_kernel(const float* __restrict__ H, const float* __restrict__ Wr2,
                             const float* __restrict__ br2, float* __restrict__ scores) {
    int wv = threadIdx.x >> 6, l = threadIdx.x & 63;
    int tok = blockIdx.x * 4 + wv;
    const float* hrow = H + (size_t)tok * DQ_;
    float4 a0 = ((const float4*)hrow)[l];
    float4 a1 = ((const float4*)hrow)[64 + l];
    float4 w0 = ((const float4*)Wr2)[l];
    float4 w1 = ((const float4*)Wr2)[64 + l];
    float s = a0.x * w0.x + a0.y * w0.y + a0.z * w0.z + a0.w * w0.w
            + a1.x * w1.x + a1.y * w1.y + a1.z * w1.z + a1.w * w1.w;
#pragma unroll
    for (int off = 32; off >= 1; off >>= 1) s += __shfl_xor(s, off);
    if (l == 0) scores[tok] = s + br2[0];
}

// ---------------- exact top-k per batch row (bitonic sort, 4096 keys) -----------
__global__ __launch_bounds__(1024) void topk_kernel(const float* __restrict__ scores,
                                                    int* __restrict__ sel_idx,
                                                    float* __restrict__ maskF) {
    __shared__ unsigned long long keys[S_];
    __shared__ unsigned char flags[S_];
    int b = blockIdx.x, t = threadIdx.x;                       // 1024 threads
    for (int i = t; i < S_; i += 1024) {
        float f = scores[b * S_ + i];
        unsigned u = __float_as_uint(f);
        u = (u & 0x80000000u) ? ~u : (u | 0x80000000u);
        keys[i] = ((unsigned long long)u << 32) | (unsigned)(S_ - 1 - i);
        flags[i] = 0;
    }
    __syncthreads();
    for (int k = 2; k <= S_; k <<= 1)
        for (int j = k >> 1; j > 0; j >>= 1) {
            for (int i = t; i < S_; i += 1024) {
                int l = i ^ j;
                if (l > i) {
                    unsigned long long a = keys[i], c = keys[l];
                    bool up = ((i & k) == 0);
                    if (up ? (a > c) : (a < c)) { keys[i] = c; keys[l] = a; }
                }
            }
            __syncthreads();
        }
    for (int i = t; i < KSEL_; i += 1024) {
        unsigned long long kk = keys[S_ - KSEL_ + i];
        int s = (S_ - 1) - (int)(kk & 0xFFFFFFFFu);
        sel_idx[b * KSEL_ + i] = s;
        flags[s] = 1;
    }
    __syncthreads();
    for (int i = t; i < S_; i += 1024)
        maskF[b * S_ + i] = flags[i] ? 1.0f : 0.0f;
}

// ---------------- gather selected rows, convert to bf16 -------------------------
__global__ void gather_kernel(const float* __restrict__ x, const int* __restrict__ sel_idx,
                              unsigned short* __restrict__ sel) {
    int jrow = blockIdx.x;               // 0..2047
    int b = jrow >> 9;
    int tok = sel_idx[jrow];
    const float* src = x + ((size_t)(b * S_ + tok)) * D_;
    int t = threadIdx.x;                 // 256
    float4 v0 = ((const float4*)src)[2 * t];
    float4 v1 = ((const float4*)src)[2 * t + 1];
    unsigned p0 = (unsigned)f2bf(v0.x) | ((unsigned)f2bf(v0.y) << 16);
    unsigned p1 = (unsigned)f2bf(v0.z) | ((unsigned)f2bf(v0.w) << 16);
    unsigned p2 = (unsigned)f2bf(v1.x) | ((unsigned)f2bf(v1.y) << 16);
    unsigned p3 = (unsigned)f2bf(v1.z) | ((unsigned)f2bf(v1.w) << 16);
    *(uint4*)(sel + (size_t)jrow * D_ + t * 8) = make_uint4(p0, p1, p2, p3);
}

// ---------------- bf16 MFMA GEMM, m97 structure, optional split-K ---------------
__global__ __launch_bounds__(256) void mfma_gemm(const unsigned short* __restrict__ A,
                                                 const unsigned short* __restrict__ Bt,
                                                 int M, int N, int K, int kspan,
                                                 const float* __restrict__ bias,
                                                 unsigned short* __restrict__ Cbf,
                                                 float* __restrict__ partial,
                                                 int epi) {
    __shared__ unsigned short As[128 * 32];
    __shared__ unsigned short Bs[128 * 32];
    const int t = threadIdx.x;
    const int w = t >> 6, l = t & 63;
    const int m0 = blockIdx.y * 128, n0 = blockIdx.x * 128;
    const int wm = (w >> 1) * 64, wn = (w & 1) * 64;
    const int kbeg = blockIdx.z * kspan;

    f32x4 acc[4][4];
    const f32x4 z = {0.f, 0.f, 0.f, 0.f};
#pragma unroll
    for (int i = 0; i < 4; i++)
#pragma unroll
        for (int j = 0; j < 4; j++) acc[i][j] = z;

    const int ra = t >> 2;
    const int ca = (t & 3) * 8;
    const unsigned short* gA0 = A + (size_t)(m0 + ra) * K + ca + kbeg;
    const unsigned short* gA1 = A + (size_t)(m0 + 64 + ra) * K + ca + kbeg;
    const unsigned short* gB0 = Bt + (size_t)(n0 + ra) * K + ca + kbeg;
    const unsigned short* gB1 = Bt + (size_t)(n0 + 64 + ra) * K + ca + kbeg;
    char* lA = (char*)As + w * 1024;
    char* lB = (char*)Bs + w * 1024;

    for (int k0 = 0; k0 < kspan; k0 += 32) {
        gload16(gA0 + k0, lA);
        gload16(gA1 + k0, lA + 4096);
        gload16(gB0 + k0, lB);
        gload16(gB1 + k0, lB + 4096);
        __syncthreads();
        bf16x8 af[4], bb[4];
#pragma unroll
        for (int i = 0; i < 4; i++) {
            af[i] = *(const bf16x8*)(As + (wm + i * 16 + (l & 15)) * 32 + (l >> 4) * 8);
            bb[i] = *(const bf16x8*)(Bs + (wn + i * 16 + (l & 15)) * 32 + (l >> 4) * 8);
        }
#pragma unroll
        for (int i = 0; i < 4; i++)
#pragma unroll
            for (int j = 0; j < 4; j++)
                acc[i][j] = __builtin_amdgcn_mfma_f32_16x16x32_bf16(af[i], bb[j], acc[i][j], 0, 0, 0);
        __syncthreads();
    }

    if (epi == 0) {
#pragma unroll
        for (int i = 0; i < 4; i++) {
            int mbase = m0 + wm + i * 16 + (l >> 4) * 4;
#pragma unroll
            for (int j = 0; j < 4; j++) {
                int n = n0 + wn + j * 16 + (l & 15);
                float bv = bias[n];
#pragma unroll
                for (int q = 0; q < 4; q++) {
                    float v = acc[i][j][q] + bv;
                    v = fmaxf(v, 0.f);
                    Cbf[(size_t)(mbase + q) * N + n] = f2bf(v);
                }
            }
        }
    } else {
        float* pseg = partial + (size_t)blockIdx.z * M * N;
#pragma unroll
        for (int i = 0; i < 4; i++) {
            int mbase = m0 + wm + i * 16 + (l >> 4) * 4;
#pragma unroll
            for (int j = 0; j < 4; j++) {
                int n = n0 + wn + j * 16 + (l & 15);
#pragma unroll
                for (int q = 0; q < 4; q++)
                    pseg[(size_t)(mbase + q) * N + n] = acc[i][j][q];
            }
        }
    }
}

// ---------------- sum 4 split-K partials + bias, scatter to out rows ------------
__global__ void reduce_scatter_kernel(const float* __restrict__ partial,
                                      const float* __restrict__ bias,
                                      const int* __restrict__ sel_idx,
                                      float* __restrict__ out) {
    int m = blockIdx.x;                  // 0..2047
    int t = threadIdx.x;                 // 256
    int brow = m >> 9;
    int tok = sel_idx[m];
    float* orow = out + ((size_t)(brow * S_ + tok)) * D_;
    const float* p0 = partial + (size_t)m * D_;
    const size_t seg = (size_t)MS_ * D_;
#pragma unroll
    for (int r = 0; r < 2; r++) {
        int c = (t + r * 256) * 4;
        float4 v0 = *(const float4*)(p0 + c);
        float4 v1 = *(const float4*)(p0 + seg + c);
        float4 v2 = *(const float4*)(p0 + 2 * seg + c);
        float4 v3 = *(const float4*)(p0 + 3 * seg + c);
        float4 bv = *(const float4*)(bias + c);
        float4 o;
        o.x = v0.x + v1.x + v2.x + v3.x + bv.x;
        o.y = v0.y + v1.y + v2.y + v3.y + bv.y;
        o.z = v0.z + v1.z + v2.z + v3.z + bv.z;
        o.w = v0.w + v1.w + v2.w + v3.w + bv.w;
        *(float4*)(orow + c) = o;
    }
}

extern "C" void kernel_launch(void* const* d_in, const int* in_sizes, int n_in,
                              void* d_out, int out_size, void* d_ws, size_t ws_size,
                              hipStream_t stream) {
    const float* x   = (const float*)d_in[0];
    const float* Wr1 = (const float*)d_in[1];
    const float* br1 = (const float*)d_in[2];
    const float* Wr2 = (const float*)d_in[3];
    const float* br2 = (const float*)d_in[4];
    const float* Wf1 = (const float*)d_in[5];
    const float* bf1 = (const float*)d_in[6];
    const float* Wf2 = (const float*)d_in[7];
    const float* bf2 = (const float*)d_in[8];
    float* out = (float*)d_out;
    char* ws = (char*)d_ws;

    // ---- workspace layout (MiB offsets, phase-overlapped) ----
    // phase 1 (router): xh 0-64 | xl 64-128 | h 128-160 | whiT 160-162 | wloT 162-164
    //                   scores 168 | sel_idx 169
    // phase 2 (FFN):    partial 0-64 | w1t 64-96 | w2t 96-128 | h1 128-160 | sel 160-168
    unsigned short* xh   = (unsigned short*)(ws);
    unsigned short* xl   = (unsigned short*)(ws + (64u << 20));
    float* h             = (float*)(ws + (128u << 20));
    unsigned short* whiT = (unsigned short*)(ws + (160u << 20));
    unsigned short* wloT = (unsigned short*)(ws + (162u << 20));
    float* scores        = (float*)(ws + (168u << 20));
    int* sel_idx         = (int*)(ws + (169u << 20));
    float* partial       = (float*)(ws);
    unsigned short* w1t  = (unsigned short*)(ws + (64u << 20));
    unsigned short* w2t  = (unsigned short*)(ws + (96u << 20));
    unsigned short* h1   = (unsigned short*)(ws + (128u << 20));
    unsigned short* sel  = (unsigned short*)(ws + (160u << 20));
    float* maskF         = out + (size_t)B_ * S_ * D_;

    (void)in_sizes; (void)n_in; (void)out_size; (void)ws_size;

    // 1. split x into bf16 hi/lo + copy x -> out
    split_copy_kernel<<<2048, 256, 0, stream>>>(x, xh, xl, out, (M_ * D_) / 8);
    // 2. Wr1 -> whiT / wloT
    wsplit_kernel<<<dim3(DQ_ / 32, D_ / 32), dim3(32, 8), 0, stream>>>(Wr1, whiT, wloT);
    // 3. fused router hidden via bf16 MFMA (3 products, one A pass)
    router_mfma<<<dim3(M_ / 128, DQ_ / 128), 256, 0, stream>>>(xh, xl, whiT, wloT, br1, h);
    // 4. scores
    score_kernel<<<M_ / 4, 256, 0, stream>>>(h, Wr2, br2, scores);
    // 5. exact top-k + mask
    topk_kernel<<<B_, 1024, 0, stream>>>(scores, sel_idx, maskF);
    // 6. gather selected tokens -> bf16
    gather_kernel<<<MS_, 256, 0, stream>>>(x, sel_idx, sel);
    // 7. FFN weight transpose + bf16 convert
    transpose_bf16_kernel<<<dim3(DF_ / 32, D_ / 32), dim3(32, 8), 0, stream>>>(Wf1, w1t, D_, DF_);
    transpose_bf16_kernel<<<dim3(D_ / 32, DF_ / 32), dim3(32, 8), 0, stream>>>(Wf2, w2t, DF_, D_);
    // 8. FFN gemm1: h1 = bf16(relu(sel @ Wf1 + bf1))   M=2048 N=8192 K=2048
    mfma_gemm<<<dim3(DF_ / 128, MS_ / 128, 1), 256, 0, stream>>>(
        sel, w1t, MS_, DF_, D_, D_, bf1, h1, nullptr, 0);
    // 9. FFN gemm2, split-K=4 -> fp32 partials   M=2048 N=2048 K=8192
    mfma_gemm<<<dim3(D_ / 128, MS_ / 128, 4), 256, 0, stream>>>(
        h1, w2t, MS_, D_, DF_, DF_ / 4, nullptr, nullptr, partial, 2);
    // 10. reduce partials + bias, scatter into out
    reduce_scatter_kernel<<<MS_, 256, 0, stream>>>(partial, bf2, sel_idx, out);
}

// Round 5
// 543.278 us; speedup vs baseline: 1.8963x; 1.0026x over previous
//
#include <hip/hip_runtime.h>

#define B_    4
#define S_    4096
#define D_    2048
#define DQ_   512
#define DF_   8192
#define KSEL_ 512
#define M_    (B_ * S_)     // 16384
#define MS_   (B_ * KSEL_)  // 2048 selected rows

typedef __attribute__((ext_vector_type(8))) short bf16x8;
typedef __attribute__((ext_vector_type(4))) float f32x4;
typedef __attribute__((address_space(3))) void as3_void;
typedef const __attribute__((address_space(1))) void as1_cvoid;

__device__ __forceinline__ unsigned short f2bf(float f) {
    unsigned u = __float_as_uint(f);
    u += 0x7FFFu + ((u >> 16) & 1u);   // RNE
    return (unsigned short)(u >> 16);
}
__device__ __forceinline__ float bf2f(unsigned short h) {
    return __uint_as_float(((unsigned)h) << 16);
}

__device__ __forceinline__ void gload16(const void* g, void* l) {
    __builtin_amdgcn_global_load_lds((as1_cvoid*)g, (as3_void*)l, 16, 0, 0);
}

// ---------------- split x into bf16 hi/lo AND copy x -> out ---------------------
__global__ void split_copy_kernel(const float* __restrict__ x,
                                  unsigned short* __restrict__ xh,
                                  unsigned short* __restrict__ xl,
                                  float* __restrict__ out, int n8) {
    int i = blockIdx.x * blockDim.x + threadIdx.x;
    int stride = gridDim.x * blockDim.x;
    for (; i < n8; i += stride) {
        float4 a = ((const float4*)x)[2 * i];
        float4 b = ((const float4*)x)[2 * i + 1];
        ((float4*)out)[2 * i]     = a;
        ((float4*)out)[2 * i + 1] = b;
        float v[8] = {a.x, a.y, a.z, a.w, b.x, b.y, b.z, b.w};
        unsigned short hi[8], lo[8];
#pragma unroll
        for (int j = 0; j < 8; j++) {
            hi[j] = f2bf(v[j]);
            lo[j] = f2bf(v[j] - bf2f(hi[j]));
        }
        *(uint4*)(xh + (size_t)i * 8) = *(const uint4*)hi;
        *(uint4*)(xl + (size_t)i * 8) = *(const uint4*)lo;
    }
}

// ---------------- Wr1 -> whiT [DQ][D], wloT [DQ][D] (bf16, transposed) ----------
__global__ void wsplit_kernel(const float* __restrict__ W,
                              unsigned short* __restrict__ whiT,
                              unsigned short* __restrict__ wloT) {
    __shared__ float tile[32][33];
    int tx = threadIdx.x, ty = threadIdx.y;          // 32 x 8
    int n0 = blockIdx.x * 32, k0 = blockIdx.y * 32;
#pragma unroll
    for (int j = 0; j < 4; j++)
        tile[ty + j * 8][tx] = W[(size_t)(k0 + ty + j * 8) * DQ_ + n0 + tx];   // tile[k][n]
    __syncthreads();
#pragma unroll
    for (int j = 0; j < 4; j++) {
        float v = tile[tx][ty + j * 8];              // k = k0+tx, n = n0+ty+j*8
        unsigned short hi = f2bf(v);
        unsigned short lo = f2bf(v - bf2f(hi));
        size_t row = (size_t)(n0 + ty + j * 8) * D_;
        whiT[row + k0 + tx] = hi;
        wloT[row + k0 + tx] = lo;
    }
}

// ---------------- transpose + fp32->bf16 convert: out[c][r] = bf16(in[r][c]) ----
__global__ void transpose_bf16_kernel(const float* __restrict__ in,
                                      unsigned short* __restrict__ out,
                                      int R, int C) {
    __shared__ float tile[32][33];
    int tx = threadIdx.x, ty = threadIdx.y;       // 32 x 8
    int c0 = blockIdx.x * 32, r0 = blockIdx.y * 32;
#pragma unroll
    for (int j = 0; j < 4; j++)
        tile[ty + j * 8][tx] = in[(size_t)(r0 + ty + j * 8) * C + c0 + tx];
    __syncthreads();
#pragma unroll
    for (int j = 0; j < 4; j++)
        out[(size_t)(c0 + ty + j * 8) * R + r0 + tx] = f2bf(tile[tx][ty + j * 8]);
}

// ---------------- fused router GEMM: acc += Ah*Bh + Ah*Bl + Al*Bh ---------------
// LDS chunk-swizzle: chunk' = chunk ^ ((row>>1)&3) via pre-swizzled global source
// (global_load_lds writes linearly); inverse XOR applied on ds_read side.
__global__ __launch_bounds__(256) void router_mfma(const unsigned short* __restrict__ xh,
                                                   const unsigned short* __restrict__ xl,
                                                   const unsigned short* __restrict__ whiT,
                                                   const unsigned short* __restrict__ wloT,
                                                   const float* __restrict__ bias,
                                                   float* __restrict__ H) {
    __shared__ unsigned short Ah[128 * 32];
    __shared__ unsigned short Al[128 * 32];
    __shared__ unsigned short Bh[128 * 32];
    __shared__ unsigned short Bl[128 * 32];
    const int t = threadIdx.x;
    const int w = t >> 6, l = t & 63;
    const int m0 = blockIdx.x * 128, n0 = blockIdx.y * 128;
    const int wm = (w >> 1) * 64, wn = (w & 1) * 64;

    f32x4 acc[4][4];
    const f32x4 z = {0.f, 0.f, 0.f, 0.f};
#pragma unroll
    for (int i = 0; i < 4; i++)
#pragma unroll
        for (int j = 0; j < 4; j++) acc[i][j] = z;

    const int ra = t >> 2;
    const int ca = (((t & 3) ^ ((t >> 3) & 3)) * 8);      // swizzled source chunk
    const unsigned short* gAh0 = xh + (size_t)(m0 + ra) * D_ + ca;
    const unsigned short* gAh1 = xh + (size_t)(m0 + 64 + ra) * D_ + ca;
    const unsigned short* gAl0 = xl + (size_t)(m0 + ra) * D_ + ca;
    const unsigned short* gAl1 = xl + (size_t)(m0 + 64 + ra) * D_ + ca;
    const unsigned short* gBh0 = whiT + (size_t)(n0 + ra) * D_ + ca;
    const unsigned short* gBh1 = whiT + (size_t)(n0 + 64 + ra) * D_ + ca;
    const unsigned short* gBl0 = wloT + (size_t)(n0 + ra) * D_ + ca;
    const unsigned short* gBl1 = wloT + (size_t)(n0 + 64 + ra) * D_ + ca;
    char* lAh = (char*)Ah + w * 1024;
    char* lAl = (char*)Al + w * 1024;
    char* lBh = (char*)Bh + w * 1024;
    char* lBl = (char*)Bl + w * 1024;

    const int ro = (((l >> 4) ^ ((l >> 1) & 3)) * 8);     // swizzled read chunk

    for (int k0 = 0; k0 < D_; k0 += 32) {
        gload16(gAh0 + k0, lAh);
        gload16(gAh1 + k0, lAh + 4096);
        gload16(gAl0 + k0, lAl);
        gload16(gAl1 + k0, lAl + 4096);
        gload16(gBh0 + k0, lBh);
        gload16(gBh1 + k0, lBh + 4096);
        gload16(gBl0 + k0, lBl);
        gload16(gBl1 + k0, lBl + 4096);
        __syncthreads();
        bf16x8 ah[4], al[4], bh[4], bl[4];
#pragma unroll
        for (int i = 0; i < 4; i++) {
            int ar = (wm + i * 16 + (l & 15)) * 32 + ro;
            int br = (wn + i * 16 + (l & 15)) * 32 + ro;
            ah[i] = *(const bf16x8*)(Ah + ar);
            al[i] = *(const bf16x8*)(Al + ar);
            bh[i] = *(const bf16x8*)(Bh + br);
            bl[i] = *(const bf16x8*)(Bl + br);
        }
#pragma unroll
        for (int i = 0; i < 4; i++)
#pragma unroll
            for (int j = 0; j < 4; j++) {
                acc[i][j] = __builtin_amdgcn_mfma_f32_16x16x32_bf16(ah[i], bh[j], acc[i][j], 0, 0, 0);
                acc[i][j] = __builtin_amdgcn_mfma_f32_16x16x32_bf16(ah[i], bl[j], acc[i][j], 0, 0, 0);
                acc[i][j] = __builtin_amdgcn_mfma_f32_16x16x32_bf16(al[i], bh[j], acc[i][j], 0, 0, 0);
            }
        __syncthreads();
    }
#pragma unroll
    for (int i = 0; i < 4; i++) {
        int mbase = m0 + wm + i * 16 + (l >> 4) * 4;
#pragma unroll
        for (int j = 0; j < 4; j++) {
            int n = n0 + wn + j * 16 + (l & 15);
            float bv = bias[n];
#pragma unroll
            for (int q = 0; q < 4; q++)
                H[(size_t)(mbase + q) * DQ_ + n] = fmaxf(acc[i][j][q] + bv, 0.f);
        }
    }
}

// ---------------- scores = H @ Wr2 + br2 (one wave per token) -------------------
__global__ void score_kernel(const float* __restrict__ H, const float* __restrict__ Wr2,
                             const float* __restrict__ br2, float* __restrict__ scores) {
    int wv = threadIdx.x >> 6, l = threadIdx.x & 63;
    int tok = blockIdx.x * 4 + wv;
    const float* hrow = H + (size_t)tok * DQ_;
    float4 a0 = ((const float4*)hrow)[l];
    float4 a1 = ((const float4*)hrow)[64 + l];
    float4 w0 = ((const float4*)Wr2)[l];
    float4 w1 = ((const float4*)Wr2)[64 + l];
    float s = a0.x * w0.x + a0.y * w0.y + a0.z * w0.z + a0.w * w0.w
            + a1.x * w1.x + a1.y * w1.y + a1.z * w1.z + a1.w * w1.w;
#pragma unroll
    for (int off = 32; off >= 1; off >>= 1) s += __shfl_xor(s, off);
    if (l == 0) scores[tok] = s + br2[0];
}

// ---------------- exact top-k per batch row (bitonic sort, 4096 keys) -----------
__global__ __launch_bounds__(1024) void topk_kernel(const float* __restrict__ scores,
                                                    int* __restrict__ sel_idx,
                                                    float* __restrict__ maskF) {
    __shared__ unsigned long long keys[S_];
    __shared__ unsigned char flags[S_];
    int b = blockIdx.x, t = threadIdx.x;                       // 1024 threads
    for (int i = t; i < S_; i += 1024) {
        float f = scores[b * S_ + i];
        unsigned u = __float_as_uint(f);
        u = (u & 0x80000000u) ? ~u : (u | 0x80000000u);
        keys[i] = ((unsigned long long)u << 32) | (unsigned)(S_ - 1 - i);
        flags[i] = 0;
    }
    __syncthreads();
    for (int k = 2; k <= S_; k <<= 1)
        for (int j = k >> 1; j > 0; j >>= 1) {
            for (int i = t; i < S_; i += 1024) {
                int l = i ^ j;
                if (l > i) {
                    unsigned long long a = keys[i], c = keys[l];
                    bool up = ((i & k) == 0);
                    if (up ? (a > c) : (a < c)) { keys[i] = c; keys[l] = a; }
                }
            }
            __syncthreads();
        }
    for (int i = t; i < KSEL_; i += 1024) {
        unsigned long long kk = keys[S_ - KSEL_ + i];
        int s = (S_ - 1) - (int)(kk & 0xFFFFFFFFu);
        sel_idx[b * KSEL_ + i] = s;
        flags[s] = 1;
    }
    __syncthreads();
    for (int i = t; i < S_; i += 1024)
        maskF[b * S_ + i] = flags[i] ? 1.0f : 0.0f;
}

// ---------------- gather selected rows, convert to bf16 -------------------------
__global__ void gather_kernel(const float* __restrict__ x, const int* __restrict__ sel_idx,
                              unsigned short* __restrict__ sel) {
    int jrow = blockIdx.x;               // 0..2047
    int b = jrow >> 9;
    int tok = sel_idx[jrow];
    const float* src = x + ((size_t)(b * S_ + tok)) * D_;
    int t = threadIdx.x;                 // 256
    float4 v0 = ((const float4*)src)[2 * t];
    float4 v1 = ((const float4*)src)[2 * t + 1];
    unsigned p0 = (unsigned)f2bf(v0.x) | ((unsigned)f2bf(v0.y) << 16);
    unsigned p1 = (unsigned)f2bf(v0.z) | ((unsigned)f2bf(v0.w) << 16);
    unsigned p2 = (unsigned)f2bf(v1.x) | ((unsigned)f2bf(v1.y) << 16);
    unsigned p3 = (unsigned)f2bf(v1.z) | ((unsigned)f2bf(v1.w) << 16);
    *(uint4*)(sel + (size_t)jrow * D_ + t * 8) = make_uint4(p0, p1, p2, p3);
}

// ---------------- bf16 MFMA GEMM, m97 structure + LDS swizzle, opt. split-K -----
__global__ __launch_bounds__(256) void mfma_gemm(const unsigned short* __restrict__ A,
                                                 const unsigned short* __restrict__ Bt,
                                                 int M, int N, int K, int kspan,
                                                 const float* __restrict__ bias,
                                                 unsigned short* __restrict__ Cbf,
                                                 float* __restrict__ partial,
                                                 int epi) {
    __shared__ unsigned short As[128 * 32];
    __shared__ unsigned short Bs[128 * 32];
    const int t = threadIdx.x;
    const int w = t >> 6, l = t & 63;
    const int m0 = blockIdx.y * 128, n0 = blockIdx.x * 128;
    const int wm = (w >> 1) * 64, wn = (w & 1) * 64;
    const int kbeg = blockIdx.z * kspan;

    f32x4 acc[4][4];
    const f32x4 z = {0.f, 0.f, 0.f, 0.f};
#pragma unroll
    for (int i = 0; i < 4; i++)
#pragma unroll
        for (int j = 0; j < 4; j++) acc[i][j] = z;

    const int ra = t >> 2;
    const int ca = (((t & 3) ^ ((t >> 3) & 3)) * 8);      // swizzled source chunk
    const unsigned short* gA0 = A + (size_t)(m0 + ra) * K + ca + kbeg;
    const unsigned short* gA1 = A + (size_t)(m0 + 64 + ra) * K + ca + kbeg;
    const unsigned short* gB0 = Bt + (size_t)(n0 + ra) * K + ca + kbeg;
    const unsigned short* gB1 = Bt + (size_t)(n0 + 64 + ra) * K + ca + kbeg;
    char* lA = (char*)As + w * 1024;
    char* lB = (char*)Bs + w * 1024;

    const int ro = (((l >> 4) ^ ((l >> 1) & 3)) * 8);     // swizzled read chunk

    for (int k0 = 0; k0 < kspan; k0 += 32) {
        gload16(gA0 + k0, lA);
        gload16(gA1 + k0, lA + 4096);
        gload16(gB0 + k0, lB);
        gload16(gB1 + k0, lB + 4096);
        __syncthreads();
        bf16x8 af[4], bb[4];
#pragma unroll
        for (int i = 0; i < 4; i++) {
            af[i] = *(const bf16x8*)(As + (wm + i * 16 + (l & 15)) * 32 + ro);
            bb[i] = *(const bf16x8*)(Bs + (wn + i * 16 + (l & 15)) * 32 + ro);
        }
#pragma unroll
        for (int i = 0; i < 4; i++)
#pragma unroll
            for (int j = 0; j < 4; j++)
                acc[i][j] = __builtin_amdgcn_mfma_f32_16x16x32_bf16(af[i], bb[j], acc[i][j], 0, 0, 0);
        __syncthreads();
    }

    if (epi == 0) {
#pragma unroll
        for (int i = 0; i < 4; i++) {
            int mbase = m0 + wm + i * 16 + (l >> 4) * 4;
#pragma unroll
            for (int j = 0; j < 4; j++) {
                int n = n0 + wn + j * 16 + (l & 15);
                float bv = bias[n];
#pragma unroll
                for (int q = 0; q < 4; q++) {
                    float v = acc[i][j][q] + bv;
                    v = fmaxf(v, 0.f);
                    Cbf[(size_t)(mbase + q) * N + n] = f2bf(v);
                }
            }
        }
    } else {
        float* pseg = partial + (size_t)blockIdx.z * M * N;
#pragma unroll
        for (int i = 0; i < 4; i++) {
            int mbase = m0 + wm + i * 16 + (l >> 4) * 4;
#pragma unroll
            for (int j = 0; j < 4; j++) {
                int n = n0 + wn + j * 16 + (l & 15);
#pragma unroll
                for (int q = 0; q < 4; q++)
                    pseg[(size_t)(mbase + q) * N + n] = acc[i][j][q];
            }
        }
    }
}

// ---------------- sum 4 split-K partials + bias, scatter to out rows ------------
__global__ void reduce_scatter_kernel(const float* __restrict__ partial,
                                      const float* __restrict__ bias,
                                      const int* __restrict__ sel_idx,
                                      float* __restrict__ out) {
    int m = blockIdx.x;                  // 0..2047
    int t = threadIdx.x;                 // 256
    int brow = m >> 9;
    int tok = sel_idx[m];
    float* orow = out + ((size_t)(brow * S_ + tok)) * D_;
    const float* p0 = partial + (size_t)m * D_;
    const size_t seg = (size_t)MS_ * D_;
#pragma unroll
    for (int r = 0; r < 2; r++) {
        int c = (t + r * 256) * 4;
        float4 v0 = *(const float4*)(p0 + c);
        float4 v1 = *(const float4*)(p0 + seg + c);
        float4 v2 = *(const float4*)(p0 + 2 * seg + c);
        float4 v3 = *(const float4*)(p0 + 3 * seg + c);
        float4 bv = *(const float4*)(bias + c);
        float4 o;
        o.x = v0.x + v1.x + v2.x + v3.x + bv.x;
        o.y = v0.y + v1.y + v2.y + v3.y + bv.y;
        o.z = v0.z + v1.z + v2.z + v3.z + bv.z;
        o.w = v0.w + v1.w + v2.w + v3.w + bv.w;
        *(float4*)(orow + c) = o;
    }
}

extern "C" void kernel_launch(void* const* d_in, const int* in_sizes, int n_in,
                              void* d_out, int out_size, void* d_ws, size_t ws_size,
                              hipStream_t stream) {
    const float* x   = (const float*)d_in[0];
    const float* Wr1 = (const float*)d_in[1];
    const float* br1 = (const float*)d_in[2];
    const float* Wr2 = (const float*)d_in[3];
    const float* br2 = (const float*)d_in[4];
    const float* Wf1 = (const float*)d_in[5];
    const float* bf1 = (const float*)d_in[6];
    const float* Wf2 = (const float*)d_in[7];
    const float* bf2 = (const float*)d_in[8];
    float* out = (float*)d_out;
    char* ws = (char*)d_ws;

    // ---- workspace layout (MiB offsets, phase-overlapped) ----
    unsigned short* xh   = (unsigned short*)(ws);
    unsigned short* xl   = (unsigned short*)(ws + (64u << 20));
    float* h             = (float*)(ws + (128u << 20));
    unsigned short* whiT = (unsigned short*)(ws + (160u << 20));
    unsigned short* wloT = (unsigned short*)(ws + (162u << 20));
    float* scores        = (float*)(ws + (168u << 20));
    int* sel_idx         = (int*)(ws + (169u << 20));
    float* partial       = (float*)(ws);
    unsigned short* w1t  = (unsigned short*)(ws + (64u << 20));
    unsigned short* w2t  = (unsigned short*)(ws + (96u << 20));
    unsigned short* h1   = (unsigned short*)(ws + (128u << 20));
    unsigned short* sel  = (unsigned short*)(ws + (160u << 20));
    float* maskF         = out + (size_t)B_ * S_ * D_;

    (void)in_sizes; (void)n_in; (void)out_size; (void)ws_size;

    // 1. split x into bf16 hi/lo + copy x -> out
    split_copy_kernel<<<2048, 256, 0, stream>>>(x, xh, xl, out, (M_ * D_) / 8);
    // 2. Wr1 -> whiT / wloT
    wsplit_kernel<<<dim3(DQ_ / 32, D_ / 32), dim3(32, 8), 0, stream>>>(Wr1, whiT, wloT);
    // 3. fused router hidden via bf16 MFMA (3 products, one A pass)
    router_mfma<<<dim3(M_ / 128, DQ_ / 128), 256, 0, stream>>>(xh, xl, whiT, wloT, br1, h);
    // 4. scores
    score_kernel<<<M_ / 4, 256, 0, stream>>>(h, Wr2, br2, scores);
    // 5. exact top-k + mask
    topk_kernel<<<B_, 1024, 0, stream>>>(scores, sel_idx, maskF);
    // 6. gather selected tokens -> bf16
    gather_kernel<<<MS_, 256, 0, stream>>>(x, sel_idx, sel);
    // 7. FFN weight transpose + bf16 convert
    transpose_bf16_kernel<<<dim3(DF_ / 32, D_ / 32), dim3(32, 8), 0, stream>>>(Wf1, w1t, D_, DF_);
    transpose_bf16_kernel<<<dim3(D_ / 32, DF_ / 32), dim3(32, 8), 0, stream>>>(Wf2, w2t, DF_, D_);
    // 8. FFN gemm1: h1 = bf16(relu(sel @ Wf1 + bf1))   M=2048 N=8192 K=2048
    mfma_gemm<<<dim3(DF_ / 128, MS_ / 128, 1), 256, 0, stream>>>(
        sel, w1t, MS_, DF_, D_, D_, bf1, h1, nullptr, 0);
    // 9. FFN gemm2, split-K=4 -> fp32 partials   M=2048 N=2048 K=8192
    mfma_gemm<<<dim3(D_ / 128, MS_ / 128, 4), 256, 0, stream>>>(
        h1, w2t, MS_, D_, DF_, DF_ / 4, nullptr, nullptr, partial, 2);
    // 10. reduce partials + bias, scatter into out
    reduce_scatter_kernel<<<MS_, 256, 0, stream>>>(partial, bf2, sel_idx, out);
}

// Round 6
// 462.353 us; speedup vs baseline: 2.2282x; 1.1750x over previous
//
#include <hip/hip_runtime.h>

#define B_    4
#define S_    4096
#define D_    2048
#define DQ_   512
#define DF_   8192
#define KSEL_ 512
#define M_    (B_ * S_)     // 16384
#define MS_   (B_ * KSEL_)  // 2048 selected rows

typedef __attribute__((ext_vector_type(8))) short bf16x8;
typedef __attribute__((ext_vector_type(4))) float f32x4;
typedef __attribute__((address_space(3))) void as3_void;
typedef const __attribute__((address_space(1))) void as1_cvoid;

__device__ __forceinline__ unsigned short f2bf(float f) {
    unsigned u = __float_as_uint(f);
    u += 0x7FFFu + ((u >> 16) & 1u);   // RNE
    return (unsigned short)(u >> 16);
}
__device__ __forceinline__ float bf2f(unsigned short h) {
    return __uint_as_float(((unsigned)h) << 16);
}

__device__ __forceinline__ void gload16(const void* g, void* l) {
    __builtin_amdgcn_global_load_lds((as1_cvoid*)g, (as3_void*)l, 16, 0, 0);
}

// ---------------- split x into bf16 hi/lo AND copy x -> out ---------------------
__global__ void split_copy_kernel(const float* __restrict__ x,
                                  unsigned short* __restrict__ xh,
                                  unsigned short* __restrict__ xl,
                                  float* __restrict__ out, int n8) {
    int i = blockIdx.x * blockDim.x + threadIdx.x;
    int stride = gridDim.x * blockDim.x;
    for (; i < n8; i += stride) {
        float4 a = ((const float4*)x)[2 * i];
        float4 b = ((const float4*)x)[2 * i + 1];
        ((float4*)out)[2 * i]     = a;
        ((float4*)out)[2 * i + 1] = b;
        float v[8] = {a.x, a.y, a.z, a.w, b.x, b.y, b.z, b.w};
        unsigned short hi[8], lo[8];
#pragma unroll
        for (int j = 0; j < 8; j++) {
            hi[j] = f2bf(v[j]);
            lo[j] = f2bf(v[j] - bf2f(hi[j]));
        }
        *(uint4*)(xh + (size_t)i * 8) = *(const uint4*)hi;
        *(uint4*)(xl + (size_t)i * 8) = *(const uint4*)lo;
    }
}

// ---------------- Wr1 -> whiT [DQ][D], wloT [DQ][D] (bf16, transposed) ----------
__global__ void wsplit_kernel(const float* __restrict__ W,
                              unsigned short* __restrict__ whiT,
                              unsigned short* __restrict__ wloT) {
    __shared__ float tile[32][33];
    int tx = threadIdx.x, ty = threadIdx.y;          // 32 x 8
    int n0 = blockIdx.x * 32, k0 = blockIdx.y * 32;
#pragma unroll
    for (int j = 0; j < 4; j++)
        tile[ty + j * 8][tx] = W[(size_t)(k0 + ty + j * 8) * DQ_ + n0 + tx];   // tile[k][n]
    __syncthreads();
#pragma unroll
    for (int j = 0; j < 4; j++) {
        float v = tile[tx][ty + j * 8];              // k = k0+tx, n = n0+ty+j*8
        unsigned short hi = f2bf(v);
        unsigned short lo = f2bf(v - bf2f(hi));
        size_t row = (size_t)(n0 + ty + j * 8) * D_;
        whiT[row + k0 + tx] = hi;
        wloT[row + k0 + tx] = lo;
    }
}

// ---------------- transpose + fp32->bf16 convert: out[c][r] = bf16(in[r][c]) ----
__global__ void transpose_bf16_kernel(const float* __restrict__ in,
                                      unsigned short* __restrict__ out,
                                      int R, int C) {
    __shared__ float tile[32][33];
    int tx = threadIdx.x, ty = threadIdx.y;       // 32 x 8
    int c0 = blockIdx.x * 32, r0 = blockIdx.y * 32;
#pragma unroll
    for (int j = 0; j < 4; j++)
        tile[ty + j * 8][tx] = in[(size_t)(r0 + ty + j * 8) * C + c0 + tx];
    __syncthreads();
#pragma unroll
    for (int j = 0; j < 4; j++)
        out[(size_t)(c0 + ty + j * 8) * R + r0 + tx] = f2bf(tile[tx][ty + j * 8]);
}

// ---------------- fused router GEMM: acc += Ah*Bh + Ah*Bl + Al*Bh ---------------
__global__ __launch_bounds__(256) void router_mfma(const unsigned short* __restrict__ xh,
                                                   const unsigned short* __restrict__ xl,
                                                   const unsigned short* __restrict__ whiT,
                                                   const unsigned short* __restrict__ wloT,
                                                   const float* __restrict__ bias,
                                                   float* __restrict__ H) {
    __shared__ unsigned short Ah[128 * 32];
    __shared__ unsigned short Al[128 * 32];
    __shared__ unsigned short Bh[128 * 32];
    __shared__ unsigned short Bl[128 * 32];
    const int t = threadIdx.x;
    const int w = t >> 6, l = t & 63;
    const int m0 = blockIdx.x * 128, n0 = blockIdx.y * 128;
    const int wm = (w >> 1) * 64, wn = (w & 1) * 64;

    f32x4 acc[4][4];
    const f32x4 z = {0.f, 0.f, 0.f, 0.f};
#pragma unroll
    for (int i = 0; i < 4; i++)
#pragma unroll
        for (int j = 0; j < 4; j++) acc[i][j] = z;

    const int ra = t >> 2;
    const int ca = (((t & 3) ^ ((t >> 3) & 3)) * 8);      // swizzled source chunk
    const unsigned short* gAh0 = xh + (size_t)(m0 + ra) * D_ + ca;
    const unsigned short* gAh1 = xh + (size_t)(m0 + 64 + ra) * D_ + ca;
    const unsigned short* gAl0 = xl + (size_t)(m0 + ra) * D_ + ca;
    const unsigned short* gAl1 = xl + (size_t)(m0 + 64 + ra) * D_ + ca;
    const unsigned short* gBh0 = whiT + (size_t)(n0 + ra) * D_ + ca;
    const unsigned short* gBh1 = whiT + (size_t)(n0 + 64 + ra) * D_ + ca;
    const unsigned short* gBl0 = wloT + (size_t)(n0 + ra) * D_ + ca;
    const unsigned short* gBl1 = wloT + (size_t)(n0 + 64 + ra) * D_ + ca;
    char* lAh = (char*)Ah + w * 1024;
    char* lAl = (char*)Al + w * 1024;
    char* lBh = (char*)Bh + w * 1024;
    char* lBl = (char*)Bl + w * 1024;

    const int ro = (((l >> 4) ^ ((l >> 1) & 3)) * 8);     // swizzled read chunk

    for (int k0 = 0; k0 < D_; k0 += 32) {
        gload16(gAh0 + k0, lAh);
        gload16(gAh1 + k0, lAh + 4096);
        gload16(gAl0 + k0, lAl);
        gload16(gAl1 + k0, lAl + 4096);
        gload16(gBh0 + k0, lBh);
        gload16(gBh1 + k0, lBh + 4096);
        gload16(gBl0 + k0, lBl);
        gload16(gBl1 + k0, lBl + 4096);
        __syncthreads();
        bf16x8 ah[4], al[4], bh[4], bl[4];
#pragma unroll
        for (int i = 0; i < 4; i++) {
            int ar = (wm + i * 16 + (l & 15)) * 32 + ro;
            int br = (wn + i * 16 + (l & 15)) * 32 + ro;
            ah[i] = *(const bf16x8*)(Ah + ar);
            al[i] = *(const bf16x8*)(Al + ar);
            bh[i] = *(const bf16x8*)(Bh + br);
            bl[i] = *(const bf16x8*)(Bl + br);
        }
#pragma unroll
        for (int i = 0; i < 4; i++)
#pragma unroll
            for (int j = 0; j < 4; j++) {
                acc[i][j] = __builtin_amdgcn_mfma_f32_16x16x32_bf16(ah[i], bh[j], acc[i][j], 0, 0, 0);
                acc[i][j] = __builtin_amdgcn_mfma_f32_16x16x32_bf16(ah[i], bl[j], acc[i][j], 0, 0, 0);
                acc[i][j] = __builtin_amdgcn_mfma_f32_16x16x32_bf16(al[i], bh[j], acc[i][j], 0, 0, 0);
            }
        __syncthreads();
    }
#pragma unroll
    for (int i = 0; i < 4; i++) {
        int mbase = m0 + wm + i * 16 + (l >> 4) * 4;
#pragma unroll
        for (int j = 0; j < 4; j++) {
            int n = n0 + wn + j * 16 + (l & 15);
            float bv = bias[n];
#pragma unroll
            for (int q = 0; q < 4; q++)
                H[(size_t)(mbase + q) * DQ_ + n] = fmaxf(acc[i][j][q] + bv, 0.f);
        }
    }
}

// ---------------- scores = H @ Wr2 + br2 (one wave per token) -------------------
__global__ void score_kernel(const float* __restrict__ H, const float* __restrict__ Wr2,
                             const float* __restrict__ br2, float* __restrict__ scores) {
    int wv = threadIdx.x >> 6, l = threadIdx.x & 63;
    int tok = blockIdx.x * 4 + wv;
    const float* hrow = H + (size_t)tok * DQ_;
    float4 a0 = ((const float4*)hrow)[l];
    float4 a1 = ((const float4*)hrow)[64 + l];
    float4 w0 = ((const float4*)Wr2)[l];
    float4 w1 = ((const float4*)Wr2)[64 + l];
    float s = a0.x * w0.x + a0.y * w0.y + a0.z * w0.z + a0.w * w0.w
            + a1.x * w1.x + a1.y * w1.y + a1.z * w1.z + a1.w * w1.w;
#pragma unroll
    for (int off = 32; off >= 1; off >>= 1) s += __shfl_xor(s, off);
    if (l == 0) scores[tok] = s + br2[0];
}

// ---------------- exact top-k per batch row (bitonic sort, 4096 keys) -----------
__global__ __launch_bounds__(1024) void topk_kernel(const float* __restrict__ scores,
                                                    int* __restrict__ sel_idx,
                                                    float* __restrict__ maskF) {
    __shared__ unsigned long long keys[S_];
    __shared__ unsigned char flags[S_];
    int b = blockIdx.x, t = threadIdx.x;                       // 1024 threads
    for (int i = t; i < S_; i += 1024) {
        float f = scores[b * S_ + i];
        unsigned u = __float_as_uint(f);
        u = (u & 0x80000000u) ? ~u : (u | 0x80000000u);
        keys[i] = ((unsigned long long)u << 32) | (unsigned)(S_ - 1 - i);
        flags[i] = 0;
    }
    __syncthreads();
    for (int k = 2; k <= S_; k <<= 1)
        for (int j = k >> 1; j > 0; j >>= 1) {
            for (int i = t; i < S_; i += 1024) {
                int l = i ^ j;
                if (l > i) {
                    unsigned long long a = keys[i], c = keys[l];
                    bool up = ((i & k) == 0);
                    if (up ? (a > c) : (a < c)) { keys[i] = c; keys[l] = a; }
                }
            }
            __syncthreads();
        }
    for (int i = t; i < KSEL_; i += 1024) {
        unsigned long long kk = keys[S_ - KSEL_ + i];
        int s = (S_ - 1) - (int)(kk & 0xFFFFFFFFu);
        sel_idx[b * KSEL_ + i] = s;
        flags[s] = 1;
    }
    __syncthreads();
    for (int i = t; i < S_; i += 1024)
        maskF[b * S_ + i] = flags[i] ? 1.0f : 0.0f;
}

// ---------------- gather selected rows, convert to bf16 -------------------------
__global__ void gather_kernel(const float* __restrict__ x, const int* __restrict__ sel_idx,
                              unsigned short* __restrict__ sel) {
    int jrow = blockIdx.x;               // 0..2047
    int b = jrow >> 9;
    int tok = sel_idx[jrow];
    const float* src = x + ((size_t)(b * S_ + tok)) * D_;
    int t = threadIdx.x;                 // 256
    float4 v0 = ((const float4*)src)[2 * t];
    float4 v1 = ((const float4*)src)[2 * t + 1];
    unsigned p0 = (unsigned)f2bf(v0.x) | ((unsigned)f2bf(v0.y) << 16);
    unsigned p1 = (unsigned)f2bf(v0.z) | ((unsigned)f2bf(v0.w) << 16);
    unsigned p2 = (unsigned)f2bf(v1.x) | ((unsigned)f2bf(v1.y) << 16);
    unsigned p3 = (unsigned)f2bf(v1.z) | ((unsigned)f2bf(v1.w) << 16);
    *(uint4*)(sel + (size_t)jrow * D_ + t * 8) = make_uint4(p0, p1, p2, p3);
}

// ======== 256x256 8-wave pipelined bf16 GEMM, BK=64, dbuf LDS, counted vmcnt ====
// A [M][K] bf16 rm, Bt [N][K] bf16 rm. Block tile 256x256, 512 thr (8 waves 2x4),
// per-wave C 128x64. LDS 2buf x (A 32KB + B 32KB) = 128 KiB -> 1 block/CU.
// T4: main loop waits vmcnt(8) (tile kt done, tile kt+1 still in flight).
// Swizzle: LDS[row][chunk] holds global chunk (chunk ^ (row&7)); read applies same.
// epi==0: Cbf = bf16(relu(acc+bias)); else: partial[z*M*N + ...] = acc (fp32).
#define STAGEAB(bufp, ktX) do {                                                   \
    const unsigned short* a_ = gA + (size_t)(ktX) * 64;                           \
    const unsigned short* b_ = gB + (size_t)(ktX) * 64;                           \
    char* la_ = (char*)(&lds[bufp][0][0]) + w * 1024;                             \
    char* lb_ = (char*)(&lds[bufp][1][0]) + w * 1024;                             \
    gload16(a_,                      la_);                                        \
    gload16(a_ +  64 * (size_t)K,    la_ + 8192);                                 \
    gload16(a_ + 128 * (size_t)K,    la_ + 16384);                                \
    gload16(a_ + 192 * (size_t)K,    la_ + 24576);                                \
    gload16(b_,                      lb_);                                        \
    gload16(b_ +  64 * (size_t)K,    lb_ + 8192);                                 \
    gload16(b_ + 128 * (size_t)K,    lb_ + 16384);                                \
    gload16(b_ + 192 * (size_t)K,    lb_ + 24576);                                \
  } while (0)

#define PHASE256(mh, kk, LOADB) do {                                              \
    const int sw_ = (((kk) * 4 + (l >> 4)) ^ (l & 7)) * 8;                        \
    if (LOADB) {                                                                  \
      _Pragma("unroll")                                                           \
      for (int n = 0; n < 4; n++)                                                 \
        bfr[n] = *(const bf16x8*)(LB + (wc * 64 + n * 16 + (l & 15)) * 64 + sw_); \
    }                                                                             \
    _Pragma("unroll")                                                             \
    for (int m = 0; m < 4; m++)                                                   \
      afr[m] = *(const bf16x8*)(LA + (wr * 128 + (mh) * 64 + m * 16 + (l & 15)) * 64 + sw_); \
    __builtin_amdgcn_s_barrier();                                                 \
    __builtin_amdgcn_s_setprio(1);                                                \
    _Pragma("unroll")                                                             \
    for (int m = 0; m < 4; m++)                                                   \
      _Pragma("unroll")                                                           \
      for (int n = 0; n < 4; n++)                                                 \
        acc[(mh) * 4 + m][n] =                                                    \
            __builtin_amdgcn_mfma_f32_16x16x32_bf16(afr[m], bfr[n], acc[(mh) * 4 + m][n], 0, 0, 0); \
    __builtin_amdgcn_s_setprio(0);                                                \
    __builtin_amdgcn_s_barrier();                                                 \
  } while (0)

__global__ __launch_bounds__(512) void mfma_gemm256(const unsigned short* __restrict__ A,
                                                    const unsigned short* __restrict__ Bt,
                                                    int M, int N, int K, int kspan,
                                                    const float* __restrict__ bias,
                                                    unsigned short* __restrict__ Cbf,
                                                    float* __restrict__ partial,
                                                    int epi) {
    __shared__ unsigned short lds[2][2][256 * 64];   // [buf][A|B][row*64 + elem]
    const int t = threadIdx.x;
    const int w = t >> 6, l = t & 63;
    const int m0 = blockIdx.y * 256, n0 = blockIdx.x * 256;
    const int wr = w >> 2, wc = w & 3;               // wave -> (2 x 4) C grid
    const int kbeg = blockIdx.z * kspan;
    const int NT = kspan / 64;

    f32x4 acc[8][4];
    const f32x4 zz = {0.f, 0.f, 0.f, 0.f};
#pragma unroll
    for (int m = 0; m < 8; m++)
#pragma unroll
        for (int n = 0; n < 4; n++) acc[m][n] = zz;

    // staging: thread t covers row (t>>3) (+q*64), LDS chunk t&7 <- global chunk (t&7)^(row&7)
    const int srow = t >> 3;
    const int sch8 = (((t & 7) ^ ((t >> 3) & 7)) * 8);
    const unsigned short* gA = A + (size_t)(m0 + srow) * K + kbeg + sch8;
    const unsigned short* gB = Bt + (size_t)(n0 + srow) * K + kbeg + sch8;

    STAGEAB(0, 0);
    STAGEAB(1, 1);

    bf16x8 afr[4], bfr[4];
    for (int kt = 0; kt < NT; ++kt) {
        if (kt + 1 < NT) { asm volatile("s_waitcnt vmcnt(8)" ::: "memory"); }
        else             { asm volatile("s_waitcnt vmcnt(0)" ::: "memory"); }
        __builtin_amdgcn_s_barrier();
        __builtin_amdgcn_sched_barrier(0);
        const int cur = kt & 1;
        const unsigned short* LA = &lds[cur][0][0];
        const unsigned short* LB = &lds[cur][1][0];
        PHASE256(0, 0, 1);     // loads B[kk0], A[mh0,kk0]
        PHASE256(1, 0, 0);     //               A[mh1,kk0]
        PHASE256(0, 1, 1);     // loads B[kk1], A[mh0,kk1]
        PHASE256(1, 1, 0);     //               A[mh1,kk1]
        __builtin_amdgcn_sched_barrier(0);
        if (kt + 2 < NT) STAGEAB(cur, kt + 2);
    }

    if (epi == 0) {
#pragma unroll
        for (int m = 0; m < 8; m++) {
            int rowb = m0 + wr * 128 + m * 16 + (l >> 4) * 4;
#pragma unroll
            for (int n = 0; n < 4; n++) {
                int col = n0 + wc * 64 + n * 16 + (l & 15);
                float bv = bias[col];
#pragma unroll
                for (int q = 0; q < 4; q++) {
                    float v = fmaxf(acc[m][n][q] + bv, 0.f);
                    Cbf[(size_t)(rowb + q) * N + col] = f2bf(v);
                }
            }
        }
    } else {
        float* pseg = partial + (size_t)blockIdx.z * M * N;
#pragma unroll
        for (int m = 0; m < 8; m++) {
            int rowb = m0 + wr * 128 + m * 16 + (l >> 4) * 4;
#pragma unroll
            for (int n = 0; n < 4; n++) {
                int col = n0 + wc * 64 + n * 16 + (l & 15);
#pragma unroll
                for (int q = 0; q < 4; q++)
                    pseg[(size_t)(rowb + q) * N + col] = acc[m][n][q];
            }
        }
    }
}

// ---------------- sum 4 split-K partials + bias, scatter to out rows ------------
__global__ void reduce_scatter_kernel(const float* __restrict__ partial,
                                      const float* __restrict__ bias,
                                      const int* __restrict__ sel_idx,
                                      float* __restrict__ out) {
    int m = blockIdx.x;                  // 0..2047
    int t = threadIdx.x;                 // 256
    int brow = m >> 9;
    int tok = sel_idx[m];
    float* orow = out + ((size_t)(brow * S_ + tok)) * D_;
    const float* p0 = partial + (size_t)m * D_;
    const size_t seg = (size_t)MS_ * D_;
#pragma unroll
    for (int r = 0; r < 2; r++) {
        int c = (t + r * 256) * 4;
        float4 v0 = *(const float4*)(p0 + c);
        float4 v1 = *(const float4*)(p0 + seg + c);
        float4 v2 = *(const float4*)(p0 + 2 * seg + c);
        float4 v3 = *(const float4*)(p0 + 3 * seg + c);
        float4 bv = *(const float4*)(bias + c);
        float4 o;
        o.x = v0.x + v1.x + v2.x + v3.x + bv.x;
        o.y = v0.y + v1.y + v2.y + v3.y + bv.y;
        o.z = v0.z + v1.z + v2.z + v3.z + bv.z;
        o.w = v0.w + v1.w + v2.w + v3.w + bv.w;
        *(float4*)(orow + c) = o;
    }
}

extern "C" void kernel_launch(void* const* d_in, const int* in_sizes, int n_in,
                              void* d_out, int out_size, void* d_ws, size_t ws_size,
                              hipStream_t stream) {
    const float* x   = (const float*)d_in[0];
    const float* Wr1 = (const float*)d_in[1];
    const float* br1 = (const float*)d_in[2];
    const float* Wr2 = (const float*)d_in[3];
    const float* br2 = (const float*)d_in[4];
    const float* Wf1 = (const float*)d_in[5];
    const float* bf1 = (const float*)d_in[6];
    const float* Wf2 = (const float*)d_in[7];
    const float* bf2 = (const float*)d_in[8];
    float* out = (float*)d_out;
    char* ws = (char*)d_ws;

    // ---- workspace layout (MiB offsets, phase-overlapped) ----
    unsigned short* xh   = (unsigned short*)(ws);
    unsigned short* xl   = (unsigned short*)(ws + (64u << 20));
    float* h             = (float*)(ws + (128u << 20));
    unsigned short* whiT = (unsigned short*)(ws + (160u << 20));
    unsigned short* wloT = (unsigned short*)(ws + (162u << 20));
    float* scores        = (float*)(ws + (168u << 20));
    int* sel_idx         = (int*)(ws + (169u << 20));
    float* partial       = (float*)(ws);
    unsigned short* w1t  = (unsigned short*)(ws + (64u << 20));
    unsigned short* w2t  = (unsigned short*)(ws + (96u << 20));
    unsigned short* h1   = (unsigned short*)(ws + (128u << 20));
    unsigned short* sel  = (unsigned short*)(ws + (160u << 20));
    float* maskF         = out + (size_t)B_ * S_ * D_;

    (void)in_sizes; (void)n_in; (void)out_size; (void)ws_size;

    // 1. split x into bf16 hi/lo + copy x -> out
    split_copy_kernel<<<2048, 256, 0, stream>>>(x, xh, xl, out, (M_ * D_) / 8);
    // 2. Wr1 -> whiT / wloT
    wsplit_kernel<<<dim3(DQ_ / 32, D_ / 32), dim3(32, 8), 0, stream>>>(Wr1, whiT, wloT);
    // 3. fused router hidden via bf16 MFMA (3 products, one A pass)
    router_mfma<<<dim3(M_ / 128, DQ_ / 128), 256, 0, stream>>>(xh, xl, whiT, wloT, br1, h);
    // 4. scores
    score_kernel<<<M_ / 4, 256, 0, stream>>>(h, Wr2, br2, scores);
    // 5. exact top-k + mask
    topk_kernel<<<B_, 1024, 0, stream>>>(scores, sel_idx, maskF);
    // 6. gather selected tokens -> bf16
    gather_kernel<<<MS_, 256, 0, stream>>>(x, sel_idx, sel);
    // 7. FFN weight transpose + bf16 convert
    transpose_bf16_kernel<<<dim3(DF_ / 32, D_ / 32), dim3(32, 8), 0, stream>>>(Wf1, w1t, D_, DF_);
    transpose_bf16_kernel<<<dim3(D_ / 32, DF_ / 32), dim3(32, 8), 0, stream>>>(Wf2, w2t, DF_, D_);
    // 8. FFN gemm1: h1 = bf16(relu(sel @ Wf1 + bf1))   M=2048 N=8192 K=2048
    mfma_gemm256<<<dim3(DF_ / 256, MS_ / 256, 1), 512, 0, stream>>>(
        sel, w1t, MS_, DF_, D_, D_, bf1, h1, nullptr, 0);
    // 9. FFN gemm2, split-K=4 -> fp32 partials   M=2048 N=2048 K=8192
    mfma_gemm256<<<dim3(D_ / 256, MS_ / 256, 4), 512, 0, stream>>>(
        h1, w2t, MS_, D_, DF_, DF_ / 4, nullptr, nullptr, partial, 1);
    // 10. reduce partials + bias, scatter into out
    reduce_scatter_kernel<<<MS_, 256, 0, stream>>>(partial, bf2, sel_idx, out);
}